// Round 11
// baseline (546.804 us; speedup 1.0000x reference)
//
#include <hip/hip_runtime.h>

// ---------------------------------------------------------------------------
// GraphUNet on MI355X.  Round-11: popc_aug v3 — 512-thread blocks (8 waves ->
// 16+ waves/CU at the fixed 528-block TRI grid; the r9/r10 versions were
// latency-bound at 2 waves/SIMD), ds_read_b128 mask reads (w-pairs).
// Rest identical to round 10.
// ---------------------------------------------------------------------------

typedef __attribute__((ext_vector_type(8))) short bf16x8;
typedef __attribute__((ext_vector_type(4))) short s16x4;
typedef __attribute__((ext_vector_type(4))) float f32x4;

__device__ __forceinline__ short f2bf(float f) {
    unsigned u = __builtin_bit_cast(unsigned, f);
    u += 0x7FFFu + ((u >> 16) & 1u);          // RNE
    return (short)(u >> 16);
}
__device__ __forceinline__ float bf2f(short s) {
    unsigned u = ((unsigned)(unsigned short)s) << 16;
    return __builtin_bit_cast(float, u);
}

#define GLL16(gsrc, ldst)                                                        \
    __builtin_amdgcn_global_load_lds(                                            \
        (__attribute__((address_space(1))) void*)(gsrc),                         \
        (__attribute__((address_space(3))) void*)(ldst), 16, 0, 0)

// ---------------------------------------------------------------------------
// bf16 BT GEMM: C(MxN) = A(MxK) @ B^T, B stored N x K row-major.
// MODE 0: Ah@Bh ; 1: +Ah@Bl ; 2: +Al@Bh   (lo*lo dropped, ~2^-18 rel)
// EPI 0: fp32 partial slice [z][M][N]
// EPI 1: fp32 mirrored square slices (TRI: blocks by>bx exit)
// EPI 3: fp32 TRANSPOSED partial slice [z][N][M] (f32x4 stores)
// ---------------------------------------------------------------------------
template<int MODE, int EPI>
__global__ __launch_bounds__(256, 2)
void gemm_bt(const short* __restrict__ Ah, const short* __restrict__ Al,
             const short* __restrict__ Bh, const short* __restrict__ Bl,
             float* __restrict__ Cf, int M, int N, int K, int kChunk)
{
    if (EPI == 1 && (int)blockIdx.y > (int)blockIdx.x) return;

    __shared__ short sAh[128 * 32];
    __shared__ short sBh[128 * 32];
    __shared__ short sAl[(MODE == 2) ? 128 * 32 : 8];
    __shared__ short sBl[(MODE >= 1) ? 128 * 32 : 8];

    const int t    = threadIdx.x;
    const int lane = t & 63;
    const int wave = t >> 6;
    const int tM   = blockIdx.y * 128;
    const int tN   = blockIdx.x * 128;
    const int k0   = blockIdx.z * kChunk;

    const int wm  = (wave >> 1) * 64;
    const int wn  = (wave & 1) * 64;
    const int l15 = lane & 15;
    const int g8  = (lane >> 4) * 8;

    f32x4 acc[4][4];
    const f32x4 zero = {0.f, 0.f, 0.f, 0.f};
#pragma unroll
    for (int i = 0; i < 4; i++)
#pragma unroll
        for (int j = 0; j < 4; j++) acc[i][j] = zero;

    const int i0 = t, i1 = t + 256;
    const short* a0 = Ah + (size_t)(tM + (i0 >> 2)) * K + (i0 & 3) * 8;
    const short* a1 = Ah + (size_t)(tM + (i1 >> 2)) * K + (i1 & 3) * 8;
    const short* b0 = Bh + (size_t)(tN + (i0 >> 2)) * K + (i0 & 3) * 8;
    const short* b1 = Bh + (size_t)(tN + (i1 >> 2)) * K + (i1 & 3) * 8;
    const short *bl0 = nullptr, *bl1 = nullptr, *al0 = nullptr, *al1 = nullptr;
    if (MODE >= 1) {
        bl0 = Bl + (size_t)(tN + (i0 >> 2)) * K + (i0 & 3) * 8;
        bl1 = Bl + (size_t)(tN + (i1 >> 2)) * K + (i1 & 3) * 8;
    }
    if (MODE == 2) {
        al0 = Al + (size_t)(tM + (i0 >> 2)) * K + (i0 & 3) * 8;
        al1 = Al + (size_t)(tM + (i1 >> 2)) * K + (i1 & 3) * 8;
    }

    for (int kb = k0; kb < k0 + kChunk; kb += 32) {
        GLL16(a0 + kb, &sAh[i0 * 8]);
        GLL16(a1 + kb, &sAh[i1 * 8]);
        GLL16(b0 + kb, &sBh[i0 * 8]);
        GLL16(b1 + kb, &sBh[i1 * 8]);
        if (MODE >= 1) { GLL16(bl0 + kb, &sBl[i0 * 8]); GLL16(bl1 + kb, &sBl[i1 * 8]); }
        if (MODE == 2) { GLL16(al0 + kb, &sAl[i0 * 8]); GLL16(al1 + kb, &sAl[i1 * 8]); }
        __syncthreads();

        bf16x8 aF[4], bF[4], aL[4], bL[4];
#pragma unroll
        for (int i = 0; i < 4; i++)
            aF[i] = *(const bf16x8*)&sAh[(wm + i * 16 + l15) * 32 + g8];
#pragma unroll
        for (int j = 0; j < 4; j++)
            bF[j] = *(const bf16x8*)&sBh[(wn + j * 16 + l15) * 32 + g8];
        if (MODE >= 1)
#pragma unroll
            for (int j = 0; j < 4; j++)
                bL[j] = *(const bf16x8*)&sBl[(wn + j * 16 + l15) * 32 + g8];
        if (MODE == 2)
#pragma unroll
            for (int i = 0; i < 4; i++)
                aL[i] = *(const bf16x8*)&sAl[(wm + i * 16 + l15) * 32 + g8];

#pragma unroll
        for (int i = 0; i < 4; i++)
#pragma unroll
            for (int j = 0; j < 4; j++) {
                acc[i][j] = __builtin_amdgcn_mfma_f32_16x16x32_bf16(aF[i], bF[j], acc[i][j], 0, 0, 0);
                if (MODE >= 1)
                    acc[i][j] = __builtin_amdgcn_mfma_f32_16x16x32_bf16(aF[i], bL[j], acc[i][j], 0, 0, 0);
                if (MODE == 2)
                    acc[i][j] = __builtin_amdgcn_mfma_f32_16x16x32_bf16(aL[i], bF[j], acc[i][j], 0, 0, 0);
            }
        __syncthreads();
    }

    // C/D layout: col=lane&15, row=(lane>>4)*4+reg  [m89-verified]
    const int r4 = (lane >> 4) * 4;
    if (EPI == 3) {
        float* CT = Cf + (size_t)blockIdx.z * M * N;   // [N][M]
#pragma unroll
        for (int i = 0; i < 4; i++)
#pragma unroll
            for (int j = 0; j < 4; j++) {
                const int col   = tN + wn + j * 16 + l15;
                const int rbase = tM + wm + i * 16 + r4;
                *(f32x4*)&CT[(size_t)col * M + rbase] = acc[i][j];
            }
    } else {
        float* Cg = Cf + (size_t)blockIdx.z * M * N;
#pragma unroll
        for (int i = 0; i < 4; i++)
#pragma unroll
            for (int j = 0; j < 4; j++) {
                const int col = tN + wn + j * 16 + l15;
                float* cp = Cg + (size_t)(tM + wm + i * 16 + r4) * N + col;
#pragma unroll
                for (int r = 0; r < 4; r++) cp[(size_t)r * N] = acc[i][j][r];
            }
        if (EPI == 1 && tM != tN) {
#pragma unroll
            for (int i = 0; i < 4; i++)
#pragma unroll
                for (int j = 0; j < 4; j++) {
                    const int col   = tN + wn + j * 16 + l15;
                    const int rbase = tM + wm + i * 16 + r4;
                    *(f32x4*)&Cg[(size_t)col * N + rbase] = acc[i][j];
                }
        }
    }
}

// ---------------------------------------------------------------------------
// Utility kernels
// ---------------------------------------------------------------------------

// one-shot prep: W^T hi/lo for all 7 layers + x0 hi/lo split
__global__ void prep(const float* __restrict__ Wd0, const float* __restrict__ Wd1,
                     const float* __restrict__ Wd2, const float* __restrict__ Wd3,
                     const float* __restrict__ Wu0, const float* __restrict__ Wu1,
                     const float* __restrict__ Wu2, const float* __restrict__ x0,
                     short* __restrict__ Wth, short* __restrict__ Wtl,
                     short* __restrict__ Xh, short* __restrict__ Xl)
{
    int t = blockIdx.x * 256 + threadIdx.x;
    float v; int dst;
    if (t < 32768)       { int e = t;          v = Wd0[e]; dst = 0      + (e & 255) * 128 + (e >> 8); }
    else if (t < 98304)  { int e = t - 32768;  v = Wd1[e]; dst = 32768  + (e & 255) * 256 + (e >> 8); }
    else if (t < 163840) { int e = t - 98304;  v = Wd2[e]; dst = 98304  + (e & 255) * 256 + (e >> 8); }
    else if (t < 229376) { int e = t - 163840; v = Wd3[e]; dst = 163840 + (e & 255) * 256 + (e >> 8); }
    else if (t < 294912) { int e = t - 229376; v = Wu0[e]; dst = 229376 + (e & 255) * 256 + (e >> 8); }
    else if (t < 360448) { int e = t - 294912; v = Wu1[e]; dst = 294912 + (e & 255) * 256 + (e >> 8); }
    else if (t < 393216) { int e = t - 360448; v = Wu2[e]; dst = 360448 + (e & 127) * 256 + (e >> 7); }
    else {
        int e = t - 393216;                      // x0: 4096*128
        v = x0[e];
        short h = f2bf(v);
        Xh[e] = h; Xl[e] = f2bf(v - bf2f(h));
        return;
    }
    short h = f2bf(v);
    Wth[dst] = h; Wtl[dst] = f2bf(v - bf2f(h));
}

__global__ void build_adj_bf16(const int* __restrict__ ei, int E,
                               short* __restrict__ A, int n)
{
    int e = blockIdx.x * 256 + threadIdx.x;
    if (e >= E) return;
    int i = ei[e], j = ei[E + e];
    if (i != j) {
        A[(size_t)i * n + j] = (short)0x3F80;
        A[(size_t)j * n + i] = (short)0x3F80;
    }
}

// dense bf16 A -> CSR (<=128 nnz/row, ascending) + degree (== rowsum, exact)
__global__ void row_compact(const short* __restrict__ A, int n,
                            int* __restrict__ csr, float* __restrict__ rs)
{
    int row = blockIdx.x * 4 + (threadIdx.x >> 6);
    int lane = threadIdx.x & 63;
    const short* ar = A + (size_t)row * n;
    int* out = csr + (size_t)row * 128;
    int base = 0;
    for (int c0 = 0; c0 < n; c0 += 64) {
        short v = ar[c0 + lane];
        unsigned long long mask = __ballot(v != 0);
        if (v != 0) {
            int pos = base + __popcll(mask & ((1ull << lane) - 1ull));
            if (pos < 128) out[pos] = c0 + lane;
        }
        base += __popcll(mask);
    }
    if (lane == 0) rs[row] = (float)base;
}

// build 4096-bit neighborhood+self masks for selected rows; zero rs
__global__ void build_mask(const int* __restrict__ csr, const float* __restrict__ deg,
                           const int* __restrict__ perm,
                           unsigned long long* __restrict__ mask,
                           float* __restrict__ rs)
{
    __shared__ unsigned long long m[4][64];
    int wave = threadIdx.x >> 6, lane = threadIdx.x & 63;
    int r = blockIdx.x * 4 + wave;
    int u = perm[r];
    m[wave][lane] = 0ull;
    __syncthreads();
    int dg = (int)deg[u];
    const int* nb = csr + (size_t)u * 128;
    for (int q = lane; q < dg; q += 64) {
        int c = nb[q];
        atomicOr(&m[wave][c >> 6], 1ull << (c & 63));
    }
    if (lane == 0) {
        atomicOr(&m[wave][u >> 6], 1ull << (u & 63));
        rs[r] = 0.f;
    }
    __syncthreads();
    mask[(size_t)r * 64 + lane] = m[wave][lane];
}

// A1 = popcount(m[r1] & m[r2]), diag 0, + mirror + rowsums.  64x64 TRI tiles,
// 512 threads (8 waves -> 16+ waves/CU at 2 resident blocks).  K-chunked LDS
// (2 x 32 words, stride 34 -> 16B-aligned b128 reads).  Thread tile:
// 4 consecutive rows x 2 cols (j0, j0+32).
#define PSTR 34
__global__ __launch_bounds__(512, 4)
void popc_aug(const unsigned long long* __restrict__ mask, int kk,
              short* __restrict__ Ahs, float* __restrict__ rs)
{
    const int bx = blockIdx.x, by = blockIdx.y;
    if (by > bx) return;
    __shared__ unsigned long long a[64 * PSTR];
    __shared__ unsigned long long b[64 * PSTR];
    __shared__ float rsum[64], csum[64];
    const int t  = threadIdx.x;
    const int i0 = (t >> 5) * 4;          // 4 consecutive rows (16 groups)
    const int j0 = t & 31;                // cols j0, j0+32

    if (t < 64) { rsum[t] = 0.f; csum[t] = 0.f; }

    int acc[4][2];
#pragma unroll
    for (int qi = 0; qi < 4; qi++) { acc[qi][0] = 0; acc[qi][1] = 0; }

    for (int ch = 0; ch < 2; ch++) {
        __syncthreads();
#pragma unroll
        for (int p = 0; p < 4; p++) {
            int idx = p * 512 + t;        // 0..2047 = rr*32 + w
            int rr = idx >> 5, w = idx & 31;
            a[rr * PSTR + w] = mask[((size_t)(by * 64 + rr)) * 64 + ch * 32 + w];
            b[rr * PSTR + w] = mask[((size_t)(bx * 64 + rr)) * 64 + ch * 32 + w];
        }
        __syncthreads();
#pragma unroll 4
        for (int w = 0; w < 32; w += 2) {
            ulong2 av[4], bv[2];
#pragma unroll
            for (int q = 0; q < 4; q++) av[q] = *(const ulong2*)&a[(i0 + q) * PSTR + w];
            bv[0] = *(const ulong2*)&b[j0 * PSTR + w];
            bv[1] = *(const ulong2*)&b[(j0 + 32) * PSTR + w];
#pragma unroll
            for (int qi = 0; qi < 4; qi++)
#pragma unroll
                for (int qj = 0; qj < 2; qj++) {
                    acc[qi][qj] += __builtin_popcountll(av[qi].x & bv[qj].x);
                    acc[qi][qj] += __builtin_popcountll(av[qi].y & bv[qj].y);
                }
        }
    }

    const int gi0 = by * 64 + i0;
    float rpart[4] = {0.f, 0.f, 0.f, 0.f};
    float cpart[2] = {0.f, 0.f};
#pragma unroll
    for (int qi = 0; qi < 4; qi++)
#pragma unroll
        for (int qj = 0; qj < 2; qj++) {
            const int gj = bx * 64 + j0 + 32 * qj;
            float v = (gi0 + qi == gj) ? 0.f : (float)acc[qi][qj];
            rpart[qi] += v;
            cpart[qj] += v;
            short h = f2bf(v);
            Ahs[(size_t)(gi0 + qi) * kk + gj] = h;
            if (bx != by) Ahs[(size_t)gj * kk + gi0 + qi] = h;
        }
#pragma unroll
    for (int q = 0; q < 4; q++) atomicAdd(&rsum[i0 + q], rpart[q]);
#pragma unroll
    for (int q = 0; q < 2; q++)
        if (bx != by) atomicAdd(&csum[j0 + 32 * q], cpart[q]);
    __syncthreads();
    if (t < 64) {
        atomicAdd(&rs[by * 64 + t], rsum[t]);
        if (bx != by) atomicAdd(&rs[bx * 64 + t], csum[t]);
    }
}

// reduce transposed xw partial slices -> Z^T hi/lo  (x4 vectorized)
__global__ void z_reduce(const float* __restrict__ Cp, int S,
                         const float* __restrict__ rs,
                         short* __restrict__ Zh, short* __restrict__ Zl,
                         int n, int C)
{
    int t4 = (blockIdx.x * 256 + threadIdx.x) * 4;   // t = c*n + r layout
    int r = t4 % n;
    size_t stride = (size_t)n * C;
    f32x4 v = {0.f, 0.f, 0.f, 0.f};
    for (int s = 0; s < S; s++) v += *(const f32x4*)&Cp[t4 + s * stride];
    f32x4 rsv = *(const f32x4*)&rs[r];
    s16x4 zh, zl;
#pragma unroll
    for (int q = 0; q < 4; q++) {
        float z = v[q] / sqrtf(rsv[q] + 2.f);
        short h = f2bf(z);
        zh[q] = h; zl[q] = f2bf(z - bf2f(h));
    }
    *(s16x4*)&Zh[t4] = zh;
    *(s16x4*)&Zl[t4] = zl;
}

// reduce row-major xw partial slices -> Zf fp32 [r][C]  (x4 vectorized)
__global__ void zf_reduce(const float* __restrict__ Cp, int S,
                          const float* __restrict__ rs,
                          float* __restrict__ Zf, int n, int C)
{
    int t4 = (blockIdx.x * 256 + threadIdx.x) * 4;   // t = r*C + c
    int r = t4 / C;
    size_t stride = (size_t)n * C;
    f32x4 v = {0.f, 0.f, 0.f, 0.f};
    for (int s = 0; s < S; s++) v += *(const f32x4*)&Cp[t4 + s * stride];
    float d = 1.f / sqrtf(rs[r] + 2.f);
    v *= d;
    *(f32x4*)&Zf[t4] = v;
}

// CSR SpMM + fused GCN epilogue
template<int CN, int RELU>
__global__ __launch_bounds__(256)
void spmm_gcn(const int* __restrict__ csr, const float* __restrict__ rs,
              const float* __restrict__ Zf, const float* __restrict__ b,
              float* __restrict__ out)
{
    const int lane = threadIdx.x & 63;
    const int row  = blockIdx.x * 4 + (threadIdx.x >> 6);
    const int dg   = (int)rs[row];
    const int* nb  = csr + (size_t)row * 128;
    if (CN == 256) {
        const int c = lane * 4;
        float4 acc = {0.f, 0.f, 0.f, 0.f};
        int q = 0;
        for (; q + 4 <= dg; q += 4) {
            int j0 = nb[q], j1 = nb[q+1], j2 = nb[q+2], j3 = nb[q+3];
            float4 z0 = *(const float4*)&Zf[(size_t)j0 * CN + c];
            float4 z1 = *(const float4*)&Zf[(size_t)j1 * CN + c];
            float4 z2 = *(const float4*)&Zf[(size_t)j2 * CN + c];
            float4 z3 = *(const float4*)&Zf[(size_t)j3 * CN + c];
            acc.x += z0.x; acc.y += z0.y; acc.z += z0.z; acc.w += z0.w;
            acc.x += z1.x; acc.y += z1.y; acc.z += z1.z; acc.w += z1.w;
            acc.x += z2.x; acc.y += z2.y; acc.z += z2.z; acc.w += z2.w;
            acc.x += z3.x; acc.y += z3.y; acc.z += z3.z; acc.w += z3.w;
        }
        for (; q < dg; q++) {
            float4 z = *(const float4*)&Zf[(size_t)nb[q] * CN + c];
            acc.x += z.x; acc.y += z.y; acc.z += z.z; acc.w += z.w;
        }
        float d = 1.f / sqrtf(rs[row] + 2.f);
        float4 zi = *(const float4*)&Zf[(size_t)row * CN + c];
        float4 bb = *(const float4*)&b[c];
        float4 g;
        g.x = d * acc.x + 2.f * d * zi.x + bb.x;
        g.y = d * acc.y + 2.f * d * zi.y + bb.y;
        g.z = d * acc.z + 2.f * d * zi.z + bb.z;
        g.w = d * acc.w + 2.f * d * zi.w + bb.w;
        if (RELU) {
            g.x = fmaxf(g.x, 0.f); g.y = fmaxf(g.y, 0.f);
            g.z = fmaxf(g.z, 0.f); g.w = fmaxf(g.w, 0.f);
        }
        *(float4*)&out[(size_t)row * CN + c] = g;
    } else {
        const int c = lane * 2;
        float2 acc = {0.f, 0.f};
        int q = 0;
        for (; q + 4 <= dg; q += 4) {
            int j0 = nb[q], j1 = nb[q+1], j2 = nb[q+2], j3 = nb[q+3];
            float2 z0 = *(const float2*)&Zf[(size_t)j0 * CN + c];
            float2 z1 = *(const float2*)&Zf[(size_t)j1 * CN + c];
            float2 z2 = *(const float2*)&Zf[(size_t)j2 * CN + c];
            float2 z3 = *(const float2*)&Zf[(size_t)j3 * CN + c];
            acc.x += z0.x; acc.y += z0.y;
            acc.x += z1.x; acc.y += z1.y;
            acc.x += z2.x; acc.y += z2.y;
            acc.x += z3.x; acc.y += z3.y;
        }
        for (; q < dg; q++) {
            float2 z = *(const float2*)&Zf[(size_t)nb[q] * CN + c];
            acc.x += z.x; acc.y += z.y;
        }
        float d = 1.f / sqrtf(rs[row] + 2.f);
        float2 zi = *(const float2*)&Zf[(size_t)row * CN + c];
        float2 g;
        g.x = d * acc.x + 2.f * d * zi.x + b[c];
        g.y = d * acc.y + 2.f * d * zi.y + b[c + 1];
        if (RELU) { g.x = fmaxf(g.x, 0.f); g.y = fmaxf(g.y, 0.f); }
        *(float2*)&out[(size_t)row * CN + c] = g;
    }
}

// fused: reduce AZ slices + GCN epilogue (+inv scatter)  (x4 vectorized)
__global__ void gcn_final(const float* __restrict__ Cp, int S,
                          const short* __restrict__ Zh, const short* __restrict__ Zl,
                          const float* __restrict__ rs, const float* __restrict__ b,
                          float* __restrict__ out, short* __restrict__ oh,
                          short* __restrict__ ol, int k, int C, int relu,
                          const int* __restrict__ inv, const float* __restrict__ res)
{
    int t4 = (blockIdx.x * 256 + threadIdx.x) * 4;
    int j = t4 / C, c = t4 - j * C;
    int r = inv ? inv[j] : j;
    f32x4 v = res ? *(const f32x4*)&res[t4] : (f32x4){0.f, 0.f, 0.f, 0.f};
    if (r >= 0) {
        size_t base = (size_t)r * C + c;
        size_t stride = (size_t)k * C;
        f32x4 az = {0.f, 0.f, 0.f, 0.f};
        for (int s = 0; s < S; s++) az += *(const f32x4*)&Cp[base + s * stride];
        float d = 1.f / sqrtf(rs[r] + 2.f);
        f32x4 bb = *(const f32x4*)&b[c];
#pragma unroll
        for (int q = 0; q < 4; q++) {
            size_t zi = (size_t)(c + q) * k + r;
            float zz = bf2f(Zh[zi]) + bf2f(Zl[zi]);      // zz ~= d * xw
            float g = d * az[q] + 2.f * d * zz + bb[q];
            if (relu && g < 0.f) g = 0.f;
            v[q] += g;
        }
    }
    *(f32x4*)&out[t4] = v;
    if (oh) {
        s16x4 hh, ll;
#pragma unroll
        for (int q = 0; q < 4; q++) {
            short h = f2bf(v[q]);
            hh[q] = h; ll[q] = f2bf(v[q] - bf2f(h));
        }
        *(s16x4*)&oh[t4] = hh;
        *(s16x4*)&ol[t4] = ll;
    }
}

__global__ void score_kernel(const float* __restrict__ x,
                             const float* __restrict__ p,
                             float* __restrict__ score, int n)
{
    int row = blockIdx.x * 4 + (threadIdx.x >> 6);
    int lane = threadIdx.x & 63;
    float4 pv = ((const float4*)p)[lane];
    float4 xv = ((const float4*)(x + (size_t)row * 256))[lane];
    double nn  = (double)pv.x * pv.x + (double)pv.y * pv.y +
                 (double)pv.z * pv.z + (double)pv.w * pv.w;
    double acc = (double)xv.x * pv.x + (double)xv.y * pv.y +
                 (double)xv.z * pv.z + (double)xv.w * pv.w;
    for (int off = 32; off; off >>= 1) {
        acc += __shfl_down(acc, off);
        nn  += __shfl_down(nn, off);
    }
    if (lane == 0) score[row] = tanhf((float)(acc / sqrt(nn)));
}

__device__ __forceinline__ unsigned long long packkey(float s, int i) {
    unsigned u = __builtin_bit_cast(unsigned, s);
    u = (u & 0x80000000u) ? ~u : (u | 0x80000000u);
    return ((unsigned long long)u << 32) | (unsigned)(0xFFFFFFFFu - (unsigned)i);
}

__global__ __launch_bounds__(256)
void rank_topk(const float* __restrict__ score, int n, int k,
               int* __restrict__ perm, float* __restrict__ vals,
               int* __restrict__ inv)
{
    __shared__ unsigned long long sk[1024];
    int i = blockIdx.x * 256 + threadIdx.x;
    float s = score[i];
    unsigned long long mykey = packkey(s, i);
    int rank = 0;
    for (int jt = 0; jt < n; jt += 1024) {
#pragma unroll
        for (int q = 0; q < 4; q++) {
            int idx = jt + threadIdx.x + q * 256;
            sk[threadIdx.x + q * 256] = packkey(score[idx], idx);
        }
        __syncthreads();
#pragma unroll 16
        for (int q = 0; q < 1024; q++) rank += (sk[q] > mykey) ? 1 : 0;
        __syncthreads();
    }
    if (rank < k) { perm[rank] = i; vals[rank] = s; }
    inv[i] = (rank < k) ? rank : -1;
}

// gathered+scaled x -> hi/lo  (x4 vectorized)
__global__ void gather_x_hl(const float* __restrict__ xold,
                            const int* __restrict__ perm,
                            const float* __restrict__ vals,
                            short* __restrict__ Xh, short* __restrict__ Xl, int C)
{
    int t4 = (blockIdx.x * 256 + threadIdx.x) * 4;
    int r = t4 / C, c = t4 - r * C;
    float vv = vals[r];
    f32x4 x = *(const f32x4*)&xold[(size_t)perm[r] * C + c];
    s16x4 hh, ll;
#pragma unroll
    for (int q = 0; q < 4; q++) {
        float v = x[q] * vv;
        short h = f2bf(v);
        hh[q] = h; ll[q] = f2bf(v - bf2f(h));
    }
    *(s16x4*)&Xh[t4] = hh;
    *(s16x4*)&Xl[t4] = ll;
}

// G = (A+I)[perm,:] from bf16 A (small-int exact); zeroes rs_next  (x8 vec)
__global__ void gatherG_h(const short* __restrict__ A, int n,
                          const int* __restrict__ perm,
                          short* __restrict__ Gh, int kk,
                          float* __restrict__ rsz)
{
    int idx = blockIdx.x * 256 + threadIdx.x;
    if (idx < kk) rsz[idx] = 0.f;
    int t8 = idx * 8;
    if (t8 >= kk * n) return;
    int r = t8 / n, c0 = t8 - r * n;
    int pr = perm[r];
    bf16x8 a = *(const bf16x8*)&A[(size_t)pr * n + c0];
    if (pr >= c0 && pr < c0 + 8)
        a[pr - c0] = f2bf(bf2f(a[pr - c0]) + 1.f);
    *(bf16x8*)&Gh[t8] = a;
}

__global__ void gatherG_hl(const short* __restrict__ Ahi, const short* __restrict__ Alo,
                           int n, const int* __restrict__ perm,
                           short* __restrict__ Gh, short* __restrict__ Gl, int kk,
                           float* __restrict__ rsz)
{
    int idx = blockIdx.x * 256 + threadIdx.x;
    if (idx < kk) rsz[idx] = 0.f;
    int t8 = idx * 8;
    if (t8 >= kk * n) return;
    int r = t8 / n, c0 = t8 - r * n;
    int pr = perm[r];
    bf16x8 ah = *(const bf16x8*)&Ahi[(size_t)pr * n + c0];
    bf16x8 al = *(const bf16x8*)&Alo[(size_t)pr * n + c0];
    bf16x8 gh, gl;
#pragma unroll
    for (int q = 0; q < 8; q++) {
        float v = bf2f(ah[q]) + bf2f(al[q]) + ((c0 + q == pr) ? 1.f : 0.f);
        short h = f2bf(v);
        gh[q] = h; gl[q] = f2bf(v - bf2f(h));
    }
    *(bf16x8*)&Gh[t8] = gh;
    *(bf16x8*)&Gl[t8] = gl;
}

// fp32 mirrored slices -> A hi(/lo), rowsums  (x4 vectorized)
template<bool LO>
__global__ void aug_finish_f(const float* __restrict__ Cp, int S, int kk,
                             short* __restrict__ Ahs, short* __restrict__ Als,
                             float* __restrict__ rs)
{
    int t4 = (blockIdx.x * 256 + threadIdx.x) * 4;
    int r = t4 / kk, c0 = t4 - r * kk;
    size_t stride = (size_t)kk * kk;
    f32x4 v = {0.f, 0.f, 0.f, 0.f};
    for (int s = 0; s < S; s++) v += *(const f32x4*)&Cp[t4 + s * stride];
    if (r >= c0 && r < c0 + 4) v[r - c0] = 0.f;
    s16x4 hh, ll;
    float ws = 0.f;
#pragma unroll
    for (int q = 0; q < 4; q++) {
        short h = f2bf(v[q]);
        hh[q] = h;
        if (LO) ll[q] = f2bf(v[q] - bf2f(h));
        ws += v[q];
    }
    *(s16x4*)&Ahs[t4] = hh;
    if (LO) *(s16x4*)&Als[t4] = ll;
    for (int off = 32; off; off >>= 1) ws += __shfl_down(ws, off);
    if ((threadIdx.x & 63) == 0) atomicAdd(&rs[r], ws);
}

// ---------------------------------------------------------------------------
// Host orchestration
// ---------------------------------------------------------------------------

extern "C" void kernel_launch(void* const* d_in, const int* in_sizes, int n_in,
                              void* d_out, int out_size, void* d_ws, size_t ws_size,
                              hipStream_t stream)
{
    const float* x0  = (const float*)d_in[0];
    const int*   ei  = (const int*)d_in[1];
    const float* Wd0 = (const float*)d_in[2];  const float* bd0 = (const float*)d_in[3];
    const float* Wd1 = (const float*)d_in[4];  const float* bd1 = (const float*)d_in[5];
    const float* Wd2 = (const float*)d_in[6];  const float* bd2 = (const float*)d_in[7];
    const float* Wd3 = (const float*)d_in[8];  const float* bd3 = (const float*)d_in[9];
    const float* p1  = (const float*)d_in[10];
    const float* p2  = (const float*)d_in[11];
    const float* p3  = (const float*)d_in[12];
    const float* Wu0 = (const float*)d_in[13]; const float* bu0 = (const float*)d_in[14];
    const float* Wu1 = (const float*)d_in[15]; const float* bu1 = (const float*)d_in[16];
    const float* Wu2 = (const float*)d_in[17]; const float* bu2 = (const float*)d_in[18];

    const int E = in_sizes[1] / 2;

    char* ws = (char*)d_ws;
    size_t off = 0;
    auto alloc = [&](size_t bytes) -> void* {
        void* p = ws + off;
        off += (bytes + 255) & ~(size_t)255;
        return p;
    };
    short* A0h  = (short*)alloc((size_t)4096 * 4096 * 2);
    short* A1h  = (short*)alloc((size_t)2048 * 2048 * 2);
    short* A2h  = (short*)alloc((size_t)1024 * 1024 * 2);
    short* A2l  = (short*)alloc((size_t)1024 * 1024 * 2);
    short* A3h  = (short*)alloc((size_t)512 * 512 * 2);
    short* A3l  = (short*)alloc((size_t)512 * 512 * 2);
    short* Gh   = (short*)alloc((size_t)1024 * 2048 * 2);
    short* Gl   = (short*)alloc((size_t)512 * 1024 * 2);
    int*   csr  = (int*)alloc((size_t)4096 * 128 * 4);
    unsigned long long* maskb = (unsigned long long*)alloc((size_t)2048 * 64 * 8);
    float* Zf   = (float*)alloc((size_t)4096 * 256 * 4);
    float* Cp   = (float*)alloc((size_t)64 * 1024 * 1024);   // partial arena
    float* xs0  = (float*)alloc((size_t)4096 * 256 * 4);
    float* xs1  = (float*)alloc((size_t)2048 * 256 * 4);
    float* xs2  = (float*)alloc((size_t)1024 * 256 * 4);
    float* xu0  = (float*)alloc((size_t)4096 * 256 * 4);
    float* xu1  = (float*)alloc((size_t)2048 * 256 * 4);
    float* xu2  = (float*)alloc((size_t)1024 * 256 * 4);
    short* xu0h = (short*)alloc((size_t)4096 * 256 * 2);
    short* xu0l = (short*)alloc((size_t)4096 * 256 * 2);
    short* xu1h = (short*)alloc((size_t)2048 * 256 * 2);
    short* xu1l = (short*)alloc((size_t)2048 * 256 * 2);
    short* xu2h = (short*)alloc((size_t)1024 * 256 * 2);
    short* xu2l = (short*)alloc((size_t)1024 * 256 * 2);
    short* X0h  = (short*)alloc((size_t)4096 * 128 * 2);
    short* X0l  = (short*)alloc((size_t)4096 * 128 * 2);
    short* xah  = (short*)alloc((size_t)2048 * 256 * 2);
    short* xal  = (short*)alloc((size_t)2048 * 256 * 2);
    short* Wth  = (short*)alloc((size_t)393216 * 2);
    short* Wtl  = (short*)alloc((size_t)393216 * 2);
    short* Zh   = (short*)alloc((size_t)256 * 4096 * 2);
    short* Zl   = (short*)alloc((size_t)256 * 4096 * 2);
    float* rs0  = (float*)alloc(4096 * 4);
    float* rs1  = (float*)alloc(2048 * 4);
    float* rs2  = (float*)alloc(1024 * 4);
    float* rs3  = (float*)alloc(512 * 4);
    float* scoreb = (float*)alloc(4096 * 4);
    float* valsb  = (float*)alloc(2048 * 4);
    int*   perm1  = (int*)alloc(2048 * 4);
    int*   perm2  = (int*)alloc(1024 * 4);
    int*   perm3  = (int*)alloc(512 * 4);
    int*   inv1   = (int*)alloc(4096 * 4);
    int*   inv2   = (int*)alloc(2048 * 4);
    int*   inv3   = (int*)alloc(1024 * 4);

    // dense-A GCN layer (levels 1..3): EPI3 xw -> z_reduce -> AZ -> gcn_final
    auto gcn_dense = [&](const short* Xh, const short* Xl, int n, int Kc, int Cout,
                         const short* pAh, const short* pAl, const float* rsA,
                         int wtoff, const float* b,
                         float* out, short* oh, short* ol, int relu, int modeA,
                         int Saz, const int* inv, const float* res, int nout) {
        int Sxw = 4;
        gemm_bt<2, 3><<<dim3(Cout / 128, n / 128, Sxw), 256, 0, stream>>>(
            Xh, Xl, Wth + wtoff, Wtl + wtoff, Cp, n, Cout, Kc, Kc / Sxw);
        z_reduce<<<(n * Cout) / 1024, 256, 0, stream>>>(Cp, Sxw, rsA, Zh, Zl, n, Cout);
        dim3 g(Cout / 128, n / 128, Saz);
        if (modeA == 1)
            gemm_bt<1, 0><<<g, 256, 0, stream>>>(pAh, nullptr, Zh, Zl, Cp, n, Cout, n, n / Saz);
        else
            gemm_bt<2, 0><<<g, 256, 0, stream>>>(pAh, pAl, Zh, Zl, Cp, n, Cout, n, n / Saz);
        gcn_final<<<(nout * Cout) / 1024, 256, 0, stream>>>(
            Cp, Saz, Zh, Zl, rsA, b, out, oh, ol, n, Cout, relu, inv, res);
    };

    auto pool = [&](const float* xlev, int n, const float* p, int* perm, int* inv) {
        int k = n / 2;
        score_kernel<<<n / 4, 256, 0, stream>>>(xlev, p, scoreb, n);
        rank_topk<<<n / 256, 256, 0, stream>>>(scoreb, n, k, perm, valsb, inv);
        gather_x_hl<<<k / 4, 256, 0, stream>>>(xlev, perm, valsb, xah, xal, 256);
    };

    // ---- prep + adjacency + CSR ----
    prep<<<3584, 256, 0, stream>>>(Wd0, Wd1, Wd2, Wd3, Wu0, Wu1, Wu2, x0,
                                   Wth, Wtl, X0h, X0l);
    hipMemsetAsync(A0h, 0, (size_t)4096 * 4096 * 2, stream);
    build_adj_bf16<<<(E + 255) / 256, 256, 0, stream>>>(ei, E, A0h, 4096);
    row_compact<<<1024, 256, 0, stream>>>(A0h, 4096, csr, rs0);

    // ---- down 0 (A0 sparse): x@W -> Zf -> SpMM+epilogue ----
    gemm_bt<2, 0><<<dim3(2, 32, 4), 256, 0, stream>>>(
        X0h, X0l, Wth, Wtl, Cp, 4096, 256, 128, 32);
    zf_reduce<<<1024, 256, 0, stream>>>(Cp, 4, rs0, Zf, 4096, 256);
    spmm_gcn<256, 1><<<1024, 256, 0, stream>>>(csr, rs0, Zf, bd0, xs0);

    // ---- level 0 -> 1: pool + bitset popcount augment ----
    pool(xs0, 4096, p1, perm1, inv1);
    build_mask<<<512, 256, 0, stream>>>(csr, rs0, perm1, maskb, rs1);
    popc_aug<<<dim3(32, 32), 512, 0, stream>>>(maskb, 2048, A1h, rs1);
    gcn_dense(xah, xal, 2048, 256, 256, A1h, nullptr, rs1, 32768, bd1,
              xs1, nullptr, nullptr, 1, 1, 16, nullptr, nullptr, 2048);

    // ---- level 1 -> 2 (dense TRI) ----
    pool(xs1, 2048, p2, perm2, inv2);
    gatherG_h<<<(1024 * 2048 / 8) / 256, 256, 0, stream>>>(A1h, 2048, perm2, Gh, 1024, rs2);
    gemm_bt<0, 1><<<dim3(8, 8, 8), 256, 0, stream>>>(Gh, nullptr, Gh, nullptr, Cp, 1024, 1024, 2048, 256);
    aug_finish_f<true><<<(1024 * 1024 / 4) / 256, 256, 0, stream>>>(Cp, 8, 1024, A2h, A2l, rs2);
    gcn_dense(xah, xal, 1024, 256, 256, A2h, A2l, rs2, 98304, bd2,
              xs2, nullptr, nullptr, 1, 2, 8, nullptr, nullptr, 1024);

    // ---- level 2 -> 3 (dense TRI) ----
    pool(xs2, 1024, p3, perm3, inv3);
    gatherG_hl<<<(512 * 1024 / 8) / 256, 256, 0, stream>>>(A2h, A2l, 1024, perm3, Gh, Gl, 512, rs3);
    gemm_bt<2, 1><<<dim3(4, 4, 8), 256, 0, stream>>>(Gh, Gl, Gh, Gl, Cp, 512, 512, 1024, 128);
    aug_finish_f<true><<<(512 * 512 / 4) / 256, 256, 0, stream>>>(Cp, 8, 512, A3h, A3l, rs3);

    // ---- down 3: out scattered into xu2 = xs2 + u (inv3) ----
    gcn_dense(xah, xal, 512, 256, 256, A3h, A3l, rs3, 163840, bd3,
              xu2, xu2h, xu2l, 1, 2, 8, inv3, xs2, 1024);

    // ---- up 0: out scattered into xu1 = xs1 + u (inv2) ----
    gcn_dense(xu2h, xu2l, 1024, 256, 256, A2h, A2l, rs2, 229376, bu0,
              xu1, xu1h, xu1l, 1, 2, 8, inv2, xs1, 2048);

    // ---- up 1: out scattered into xu0 = xs0 + u (inv1) ----
    gcn_dense(xu1h, xu1l, 2048, 256, 256, A1h, nullptr, rs1, 294912, bu1,
              xu0, xu0h, xu0l, 1, 1, 16, inv1, xs0, 4096);

    // ---- up 2 (A0 sparse, Cout=128, no relu) -> d_out ----
    gemm_bt<2, 0><<<dim3(1, 32, 8), 256, 0, stream>>>(
        xu0h, xu0l, Wth + 360448, Wtl + 360448, Cp, 4096, 128, 256, 32);
    zf_reduce<<<512, 256, 0, stream>>>(Cp, 8, rs0, Zf, 4096, 128);
    spmm_gcn<128, 0><<<1024, 256, 0, stream>>>(csr, rs0, Zf, bu2, (float*)d_out);
}

// Round 12
// 525.259 us; speedup vs baseline: 1.0410x; 1.0410x over previous
//
#include <hip/hip_runtime.h>

// ---------------------------------------------------------------------------
// GraphUNet on MI355X.  Round-12: popc_aug v4 — split-K over grid.z (4 x 16
// words), int16 partial tiles, 18 KB LDS -> 8 blocks/CU (r9-r11 were stuck
// at 2 blocks/CU, latency-bound); aug_merge sums slices + LDS-transpose
// mirror + rowsums.  Rest identical to round 10.
// ---------------------------------------------------------------------------

typedef __attribute__((ext_vector_type(8))) short bf16x8;
typedef __attribute__((ext_vector_type(4))) short s16x4;
typedef __attribute__((ext_vector_type(4))) float f32x4;

__device__ __forceinline__ short f2bf(float f) {
    unsigned u = __builtin_bit_cast(unsigned, f);
    u += 0x7FFFu + ((u >> 16) & 1u);          // RNE
    return (short)(u >> 16);
}
__device__ __forceinline__ float bf2f(short s) {
    unsigned u = ((unsigned)(unsigned short)s) << 16;
    return __builtin_bit_cast(float, u);
}

#define GLL16(gsrc, ldst)                                                        \
    __builtin_amdgcn_global_load_lds(                                            \
        (__attribute__((address_space(1))) void*)(gsrc),                         \
        (__attribute__((address_space(3))) void*)(ldst), 16, 0, 0)

// ---------------------------------------------------------------------------
// bf16 BT GEMM: C(MxN) = A(MxK) @ B^T, B stored N x K row-major.
// MODE 0: Ah@Bh ; 1: +Ah@Bl ; 2: +Al@Bh   (lo*lo dropped, ~2^-18 rel)
// EPI 0: fp32 partial slice [z][M][N]
// EPI 1: fp32 mirrored square slices (TRI: blocks by>bx exit)
// EPI 3: fp32 TRANSPOSED partial slice [z][N][M] (f32x4 stores)
// ---------------------------------------------------------------------------
template<int MODE, int EPI>
__global__ __launch_bounds__(256, 2)
void gemm_bt(const short* __restrict__ Ah, const short* __restrict__ Al,
             const short* __restrict__ Bh, const short* __restrict__ Bl,
             float* __restrict__ Cf, int M, int N, int K, int kChunk)
{
    if (EPI == 1 && (int)blockIdx.y > (int)blockIdx.x) return;

    __shared__ short sAh[128 * 32];
    __shared__ short sBh[128 * 32];
    __shared__ short sAl[(MODE == 2) ? 128 * 32 : 8];
    __shared__ short sBl[(MODE >= 1) ? 128 * 32 : 8];

    const int t    = threadIdx.x;
    const int lane = t & 63;
    const int wave = t >> 6;
    const int tM   = blockIdx.y * 128;
    const int tN   = blockIdx.x * 128;
    const int k0   = blockIdx.z * kChunk;

    const int wm  = (wave >> 1) * 64;
    const int wn  = (wave & 1) * 64;
    const int l15 = lane & 15;
    const int g8  = (lane >> 4) * 8;

    f32x4 acc[4][4];
    const f32x4 zero = {0.f, 0.f, 0.f, 0.f};
#pragma unroll
    for (int i = 0; i < 4; i++)
#pragma unroll
        for (int j = 0; j < 4; j++) acc[i][j] = zero;

    const int i0 = t, i1 = t + 256;
    const short* a0 = Ah + (size_t)(tM + (i0 >> 2)) * K + (i0 & 3) * 8;
    const short* a1 = Ah + (size_t)(tM + (i1 >> 2)) * K + (i1 & 3) * 8;
    const short* b0 = Bh + (size_t)(tN + (i0 >> 2)) * K + (i0 & 3) * 8;
    const short* b1 = Bh + (size_t)(tN + (i1 >> 2)) * K + (i1 & 3) * 8;
    const short *bl0 = nullptr, *bl1 = nullptr, *al0 = nullptr, *al1 = nullptr;
    if (MODE >= 1) {
        bl0 = Bl + (size_t)(tN + (i0 >> 2)) * K + (i0 & 3) * 8;
        bl1 = Bl + (size_t)(tN + (i1 >> 2)) * K + (i1 & 3) * 8;
    }
    if (MODE == 2) {
        al0 = Al + (size_t)(tM + (i0 >> 2)) * K + (i0 & 3) * 8;
        al1 = Al + (size_t)(tM + (i1 >> 2)) * K + (i1 & 3) * 8;
    }

    for (int kb = k0; kb < k0 + kChunk; kb += 32) {
        GLL16(a0 + kb, &sAh[i0 * 8]);
        GLL16(a1 + kb, &sAh[i1 * 8]);
        GLL16(b0 + kb, &sBh[i0 * 8]);
        GLL16(b1 + kb, &sBh[i1 * 8]);
        if (MODE >= 1) { GLL16(bl0 + kb, &sBl[i0 * 8]); GLL16(bl1 + kb, &sBl[i1 * 8]); }
        if (MODE == 2) { GLL16(al0 + kb, &sAl[i0 * 8]); GLL16(al1 + kb, &sAl[i1 * 8]); }
        __syncthreads();

        bf16x8 aF[4], bF[4], aL[4], bL[4];
#pragma unroll
        for (int i = 0; i < 4; i++)
            aF[i] = *(const bf16x8*)&sAh[(wm + i * 16 + l15) * 32 + g8];
#pragma unroll
        for (int j = 0; j < 4; j++)
            bF[j] = *(const bf16x8*)&sBh[(wn + j * 16 + l15) * 32 + g8];
        if (MODE >= 1)
#pragma unroll
            for (int j = 0; j < 4; j++)
                bL[j] = *(const bf16x8*)&sBl[(wn + j * 16 + l15) * 32 + g8];
        if (MODE == 2)
#pragma unroll
            for (int i = 0; i < 4; i++)
                aL[i] = *(const bf16x8*)&sAl[(wm + i * 16 + l15) * 32 + g8];

#pragma unroll
        for (int i = 0; i < 4; i++)
#pragma unroll
            for (int j = 0; j < 4; j++) {
                acc[i][j] = __builtin_amdgcn_mfma_f32_16x16x32_bf16(aF[i], bF[j], acc[i][j], 0, 0, 0);
                if (MODE >= 1)
                    acc[i][j] = __builtin_amdgcn_mfma_f32_16x16x32_bf16(aF[i], bL[j], acc[i][j], 0, 0, 0);
                if (MODE == 2)
                    acc[i][j] = __builtin_amdgcn_mfma_f32_16x16x32_bf16(aL[i], bF[j], acc[i][j], 0, 0, 0);
            }
        __syncthreads();
    }

    // C/D layout: col=lane&15, row=(lane>>4)*4+reg  [m89-verified]
    const int r4 = (lane >> 4) * 4;
    if (EPI == 3) {
        float* CT = Cf + (size_t)blockIdx.z * M * N;   // [N][M]
#pragma unroll
        for (int i = 0; i < 4; i++)
#pragma unroll
            for (int j = 0; j < 4; j++) {
                const int col   = tN + wn + j * 16 + l15;
                const int rbase = tM + wm + i * 16 + r4;
                *(f32x4*)&CT[(size_t)col * M + rbase] = acc[i][j];
            }
    } else {
        float* Cg = Cf + (size_t)blockIdx.z * M * N;
#pragma unroll
        for (int i = 0; i < 4; i++)
#pragma unroll
            for (int j = 0; j < 4; j++) {
                const int col = tN + wn + j * 16 + l15;
                float* cp = Cg + (size_t)(tM + wm + i * 16 + r4) * N + col;
#pragma unroll
                for (int r = 0; r < 4; r++) cp[(size_t)r * N] = acc[i][j][r];
            }
        if (EPI == 1 && tM != tN) {
#pragma unroll
            for (int i = 0; i < 4; i++)
#pragma unroll
                for (int j = 0; j < 4; j++) {
                    const int col   = tN + wn + j * 16 + l15;
                    const int rbase = tM + wm + i * 16 + r4;
                    *(f32x4*)&Cg[(size_t)col * N + rbase] = acc[i][j];
                }
        }
    }
}

// ---------------------------------------------------------------------------
// Utility kernels
// ---------------------------------------------------------------------------

// one-shot prep: W^T hi/lo for all 7 layers + x0 hi/lo split
__global__ void prep(const float* __restrict__ Wd0, const float* __restrict__ Wd1,
                     const float* __restrict__ Wd2, const float* __restrict__ Wd3,
                     const float* __restrict__ Wu0, const float* __restrict__ Wu1,
                     const float* __restrict__ Wu2, const float* __restrict__ x0,
                     short* __restrict__ Wth, short* __restrict__ Wtl,
                     short* __restrict__ Xh, short* __restrict__ Xl)
{
    int t = blockIdx.x * 256 + threadIdx.x;
    float v; int dst;
    if (t < 32768)       { int e = t;          v = Wd0[e]; dst = 0      + (e & 255) * 128 + (e >> 8); }
    else if (t < 98304)  { int e = t - 32768;  v = Wd1[e]; dst = 32768  + (e & 255) * 256 + (e >> 8); }
    else if (t < 163840) { int e = t - 98304;  v = Wd2[e]; dst = 98304  + (e & 255) * 256 + (e >> 8); }
    else if (t < 229376) { int e = t - 163840; v = Wd3[e]; dst = 163840 + (e & 255) * 256 + (e >> 8); }
    else if (t < 294912) { int e = t - 229376; v = Wu0[e]; dst = 229376 + (e & 255) * 256 + (e >> 8); }
    else if (t < 360448) { int e = t - 294912; v = Wu1[e]; dst = 294912 + (e & 255) * 256 + (e >> 8); }
    else if (t < 393216) { int e = t - 360448; v = Wu2[e]; dst = 360448 + (e & 127) * 256 + (e >> 7); }
    else {
        int e = t - 393216;                      // x0: 4096*128
        v = x0[e];
        short h = f2bf(v);
        Xh[e] = h; Xl[e] = f2bf(v - bf2f(h));
        return;
    }
    short h = f2bf(v);
    Wth[dst] = h; Wtl[dst] = f2bf(v - bf2f(h));
}

__global__ void build_adj_bf16(const int* __restrict__ ei, int E,
                               short* __restrict__ A, int n)
{
    int e = blockIdx.x * 256 + threadIdx.x;
    if (e >= E) return;
    int i = ei[e], j = ei[E + e];
    if (i != j) {
        A[(size_t)i * n + j] = (short)0x3F80;
        A[(size_t)j * n + i] = (short)0x3F80;
    }
}

// dense bf16 A -> CSR (<=128 nnz/row, ascending) + degree (== rowsum, exact)
__global__ void row_compact(const short* __restrict__ A, int n,
                            int* __restrict__ csr, float* __restrict__ rs)
{
    int row = blockIdx.x * 4 + (threadIdx.x >> 6);
    int lane = threadIdx.x & 63;
    const short* ar = A + (size_t)row * n;
    int* out = csr + (size_t)row * 128;
    int base = 0;
    for (int c0 = 0; c0 < n; c0 += 64) {
        short v = ar[c0 + lane];
        unsigned long long mask = __ballot(v != 0);
        if (v != 0) {
            int pos = base + __popcll(mask & ((1ull << lane) - 1ull));
            if (pos < 128) out[pos] = c0 + lane;
        }
        base += __popcll(mask);
    }
    if (lane == 0) rs[row] = (float)base;
}

// build 4096-bit neighborhood+self masks for selected rows; zero rs
__global__ void build_mask(const int* __restrict__ csr, const float* __restrict__ deg,
                           const int* __restrict__ perm,
                           unsigned long long* __restrict__ mask,
                           float* __restrict__ rs)
{
    __shared__ unsigned long long m[4][64];
    int wave = threadIdx.x >> 6, lane = threadIdx.x & 63;
    int r = blockIdx.x * 4 + wave;
    int u = perm[r];
    m[wave][lane] = 0ull;
    __syncthreads();
    int dg = (int)deg[u];
    const int* nb = csr + (size_t)u * 128;
    for (int q = lane; q < dg; q += 64) {
        int c = nb[q];
        atomicOr(&m[wave][c >> 6], 1ull << (c & 63));
    }
    if (lane == 0) {
        atomicOr(&m[wave][u >> 6], 1ull << (u & 63));
        rs[r] = 0.f;
    }
    __syncthreads();
    mask[(size_t)r * 64 + lane] = m[wave][lane];
}

// popcount partial: slice z covers words [z*16, z*16+16).  64x64 TRI tiles,
// 18 KB LDS -> 8 blocks/CU.  int16 partial tile at Cp[(z*1024 + by*32+bx)*4096].
#define PSTR2 18
__global__ __launch_bounds__(256, 8)
void popc_aug_p(const unsigned long long* __restrict__ mask,
                short* __restrict__ Cp)
{
    const int bx = blockIdx.x, by = blockIdx.y, z = blockIdx.z;
    if (by > bx) return;
    __shared__ unsigned long long a[64 * PSTR2];
    __shared__ unsigned long long b[64 * PSTR2];
    const int t = threadIdx.x;
#pragma unroll
    for (int p = 0; p < 4; p++) {
        int idx = p * 256 + t;           // 0..1023 = rr*16 + w
        int rr = idx >> 4, w = idx & 15;
        a[rr * PSTR2 + w] = mask[((size_t)(by * 64 + rr)) * 64 + z * 16 + w];
        b[rr * PSTR2 + w] = mask[((size_t)(bx * 64 + rr)) * 64 + z * 16 + w];
    }
    __syncthreads();
    const int i0 = (t >> 4) * 4;         // 4 consecutive rows
    const int j0 = t & 15;               // cols j0 + 16*qj
    int acc[4][4];
#pragma unroll
    for (int qi = 0; qi < 4; qi++)
#pragma unroll
        for (int qj = 0; qj < 4; qj++) acc[qi][qj] = 0;
#pragma unroll
    for (int w = 0; w < 16; w += 2) {
        ulong2 av[4], bv[4];
#pragma unroll
        for (int q = 0; q < 4; q++) av[q] = *(const ulong2*)&a[(i0 + q) * PSTR2 + w];
#pragma unroll
        for (int q = 0; q < 4; q++) bv[q] = *(const ulong2*)&b[(j0 + 16 * q) * PSTR2 + w];
#pragma unroll
        for (int qi = 0; qi < 4; qi++)
#pragma unroll
            for (int qj = 0; qj < 4; qj++) {
                acc[qi][qj] += __builtin_popcountll(av[qi].x & bv[qj].x);
                acc[qi][qj] += __builtin_popcountll(av[qi].y & bv[qj].y);
            }
    }
    short* out = Cp + ((size_t)z * 1024 + (size_t)(by * 32 + bx)) * 4096;
#pragma unroll
    for (int qi = 0; qi < 4; qi++)
#pragma unroll
        for (int qj = 0; qj < 4; qj++)
            out[(i0 + qi) * 64 + j0 + 16 * qj] = (short)acc[qi][qj];
}

// merge 4 int16 slices -> A1h (bf16, diag 0) + LDS-transposed mirror + rowsums
__global__ __launch_bounds__(256)
void aug_merge(const short* __restrict__ Cp, int kk,
               short* __restrict__ Ahs, float* __restrict__ rs)
{
    const int bx = blockIdx.x, by = blockIdx.y;
    if (by > bx) return;
    __shared__ float tile[64][65];
    __shared__ float rsum[64], csum[64];
    const int t = threadIdx.x;
    const int i  = t >> 2;               // row 0..63
    const int c0 = (t & 3) * 16;         // 16 consecutive cols
    const size_t tb = (size_t)(by * 32 + bx) * 4096;
    const size_t ss = (size_t)1024 * 4096;
    if (t < 64) { rsum[t] = 0.f; csum[t] = 0.f; }

    int v[16];
#pragma unroll
    for (int q = 0; q < 16; q++) v[q] = 0;
    for (int s = 0; s < 4; s++) {
        bf16x8 p0 = *(const bf16x8*)&Cp[tb + s * ss + i * 64 + c0];
        bf16x8 p1 = *(const bf16x8*)&Cp[tb + s * ss + i * 64 + c0 + 8];
#pragma unroll
        for (int q = 0; q < 8; q++) { v[q] += (int)p0[q]; v[8 + q] += (int)p1[q]; }
    }
    const int gi = by * 64 + i;
    float rp = 0.f;
    s16x4 pk[4];
#pragma unroll
    for (int q = 0; q < 16; q++) {
        const int gj = bx * 64 + c0 + q;
        float val = (gi == gj) ? 0.f : (float)v[q];
        tile[i][c0 + q] = val;
        rp += val;
        pk[q >> 2][q & 3] = f2bf(val);
    }
#pragma unroll
    for (int q = 0; q < 4; q++)
        *(s16x4*)&Ahs[(size_t)gi * kk + bx * 64 + c0 + q * 4] = pk[q];
    __syncthreads();
    atomicAdd(&rsum[i], rp);
    if (bx != by) {
        // mirror: row i of mirror block = column i of tile
        float cpv = 0.f;
#pragma unroll
        for (int q = 0; q < 16; q++) {
            float val = tile[c0 + q][i];
            cpv += val;
            pk[q >> 2][q & 3] = f2bf(val);
        }
#pragma unroll
        for (int q = 0; q < 4; q++)
            *(s16x4*)&Ahs[(size_t)(bx * 64 + i) * kk + by * 64 + c0 + q * 4] = pk[q];
        atomicAdd(&csum[i], cpv);
    }
    __syncthreads();
    if (t < 64) {
        atomicAdd(&rs[by * 64 + t], rsum[t]);
        if (bx != by) atomicAdd(&rs[bx * 64 + t], csum[t]);
    }
}

// reduce transposed xw partial slices -> Z^T hi/lo  (x4 vectorized)
__global__ void z_reduce(const float* __restrict__ Cp, int S,
                         const float* __restrict__ rs,
                         short* __restrict__ Zh, short* __restrict__ Zl,
                         int n, int C)
{
    int t4 = (blockIdx.x * 256 + threadIdx.x) * 4;   // t = c*n + r layout
    int r = t4 % n;
    size_t stride = (size_t)n * C;
    f32x4 v = {0.f, 0.f, 0.f, 0.f};
    for (int s = 0; s < S; s++) v += *(const f32x4*)&Cp[t4 + s * stride];
    f32x4 rsv = *(const f32x4*)&rs[r];
    s16x4 zh, zl;
#pragma unroll
    for (int q = 0; q < 4; q++) {
        float z = v[q] / sqrtf(rsv[q] + 2.f);
        short h = f2bf(z);
        zh[q] = h; zl[q] = f2bf(z - bf2f(h));
    }
    *(s16x4*)&Zh[t4] = zh;
    *(s16x4*)&Zl[t4] = zl;
}

// reduce row-major xw partial slices -> Zf fp32 [r][C]  (x4 vectorized)
__global__ void zf_reduce(const float* __restrict__ Cp, int S,
                          const float* __restrict__ rs,
                          float* __restrict__ Zf, int n, int C)
{
    int t4 = (blockIdx.x * 256 + threadIdx.x) * 4;   // t = r*C + c
    int r = t4 / C;
    size_t stride = (size_t)n * C;
    f32x4 v = {0.f, 0.f, 0.f, 0.f};
    for (int s = 0; s < S; s++) v += *(const f32x4*)&Cp[t4 + s * stride];
    float d = 1.f / sqrtf(rs[r] + 2.f);
    v *= d;
    *(f32x4*)&Zf[t4] = v;
}

// CSR SpMM + fused GCN epilogue
template<int CN, int RELU>
__global__ __launch_bounds__(256)
void spmm_gcn(const int* __restrict__ csr, const float* __restrict__ rs,
              const float* __restrict__ Zf, const float* __restrict__ b,
              float* __restrict__ out)
{
    const int lane = threadIdx.x & 63;
    const int row  = blockIdx.x * 4 + (threadIdx.x >> 6);
    const int dg   = (int)rs[row];
    const int* nb  = csr + (size_t)row * 128;
    if (CN == 256) {
        const int c = lane * 4;
        float4 acc = {0.f, 0.f, 0.f, 0.f};
        int q = 0;
        for (; q + 4 <= dg; q += 4) {
            int j0 = nb[q], j1 = nb[q+1], j2 = nb[q+2], j3 = nb[q+3];
            float4 z0 = *(const float4*)&Zf[(size_t)j0 * CN + c];
            float4 z1 = *(const float4*)&Zf[(size_t)j1 * CN + c];
            float4 z2 = *(const float4*)&Zf[(size_t)j2 * CN + c];
            float4 z3 = *(const float4*)&Zf[(size_t)j3 * CN + c];
            acc.x += z0.x; acc.y += z0.y; acc.z += z0.z; acc.w += z0.w;
            acc.x += z1.x; acc.y += z1.y; acc.z += z1.z; acc.w += z1.w;
            acc.x += z2.x; acc.y += z2.y; acc.z += z2.z; acc.w += z2.w;
            acc.x += z3.x; acc.y += z3.y; acc.z += z3.z; acc.w += z3.w;
        }
        for (; q < dg; q++) {
            float4 z = *(const float4*)&Zf[(size_t)nb[q] * CN + c];
            acc.x += z.x; acc.y += z.y; acc.z += z.z; acc.w += z.w;
        }
        float d = 1.f / sqrtf(rs[row] + 2.f);
        float4 zi = *(const float4*)&Zf[(size_t)row * CN + c];
        float4 bb = *(const float4*)&b[c];
        float4 g;
        g.x = d * acc.x + 2.f * d * zi.x + bb.x;
        g.y = d * acc.y + 2.f * d * zi.y + bb.y;
        g.z = d * acc.z + 2.f * d * zi.z + bb.z;
        g.w = d * acc.w + 2.f * d * zi.w + bb.w;
        if (RELU) {
            g.x = fmaxf(g.x, 0.f); g.y = fmaxf(g.y, 0.f);
            g.z = fmaxf(g.z, 0.f); g.w = fmaxf(g.w, 0.f);
        }
        *(float4*)&out[(size_t)row * CN + c] = g;
    } else {
        const int c = lane * 2;
        float2 acc = {0.f, 0.f};
        int q = 0;
        for (; q + 4 <= dg; q += 4) {
            int j0 = nb[q], j1 = nb[q+1], j2 = nb[q+2], j3 = nb[q+3];
            float2 z0 = *(const float2*)&Zf[(size_t)j0 * CN + c];
            float2 z1 = *(const float2*)&Zf[(size_t)j1 * CN + c];
            float2 z2 = *(const float2*)&Zf[(size_t)j2 * CN + c];
            float2 z3 = *(const float2*)&Zf[(size_t)j3 * CN + c];
            acc.x += z0.x; acc.y += z0.y;
            acc.x += z1.x; acc.y += z1.y;
            acc.x += z2.x; acc.y += z2.y;
            acc.x += z3.x; acc.y += z3.y;
        }
        for (; q < dg; q++) {
            float2 z = *(const float2*)&Zf[(size_t)nb[q] * CN + c];
            acc.x += z.x; acc.y += z.y;
        }
        float d = 1.f / sqrtf(rs[row] + 2.f);
        float2 zi = *(const float2*)&Zf[(size_t)row * CN + c];
        float2 g;
        g.x = d * acc.x + 2.f * d * zi.x + b[c];
        g.y = d * acc.y + 2.f * d * zi.y + b[c + 1];
        if (RELU) { g.x = fmaxf(g.x, 0.f); g.y = fmaxf(g.y, 0.f); }
        *(float2*)&out[(size_t)row * CN + c] = g;
    }
}

// fused: reduce AZ slices + GCN epilogue (+inv scatter)  (x4 vectorized)
__global__ void gcn_final(const float* __restrict__ Cp, int S,
                          const short* __restrict__ Zh, const short* __restrict__ Zl,
                          const float* __restrict__ rs, const float* __restrict__ b,
                          float* __restrict__ out, short* __restrict__ oh,
                          short* __restrict__ ol, int k, int C, int relu,
                          const int* __restrict__ inv, const float* __restrict__ res)
{
    int t4 = (blockIdx.x * 256 + threadIdx.x) * 4;
    int j = t4 / C, c = t4 - j * C;
    int r = inv ? inv[j] : j;
    f32x4 v = res ? *(const f32x4*)&res[t4] : (f32x4){0.f, 0.f, 0.f, 0.f};
    if (r >= 0) {
        size_t base = (size_t)r * C + c;
        size_t stride = (size_t)k * C;
        f32x4 az = {0.f, 0.f, 0.f, 0.f};
        for (int s = 0; s < S; s++) az += *(const f32x4*)&Cp[base + s * stride];
        float d = 1.f / sqrtf(rs[r] + 2.f);
        f32x4 bb = *(const f32x4*)&b[c];
#pragma unroll
        for (int q = 0; q < 4; q++) {
            size_t zi = (size_t)(c + q) * k + r;
            float zz = bf2f(Zh[zi]) + bf2f(Zl[zi]);      // zz ~= d * xw
            float g = d * az[q] + 2.f * d * zz + bb[q];
            if (relu && g < 0.f) g = 0.f;
            v[q] += g;
        }
    }
    *(f32x4*)&out[t4] = v;
    if (oh) {
        s16x4 hh, ll;
#pragma unroll
        for (int q = 0; q < 4; q++) {
            short h = f2bf(v[q]);
            hh[q] = h; ll[q] = f2bf(v[q] - bf2f(h));
        }
        *(s16x4*)&oh[t4] = hh;
        *(s16x4*)&ol[t4] = ll;
    }
}

__global__ void score_kernel(const float* __restrict__ x,
                             const float* __restrict__ p,
                             float* __restrict__ score, int n)
{
    int row = blockIdx.x * 4 + (threadIdx.x >> 6);
    int lane = threadIdx.x & 63;
    float4 pv = ((const float4*)p)[lane];
    float4 xv = ((const float4*)(x + (size_t)row * 256))[lane];
    double nn  = (double)pv.x * pv.x + (double)pv.y * pv.y +
                 (double)pv.z * pv.z + (double)pv.w * pv.w;
    double acc = (double)xv.x * pv.x + (double)xv.y * pv.y +
                 (double)xv.z * pv.z + (double)xv.w * pv.w;
    for (int off = 32; off; off >>= 1) {
        acc += __shfl_down(acc, off);
        nn  += __shfl_down(nn, off);
    }
    if (lane == 0) score[row] = tanhf((float)(acc / sqrt(nn)));
}

__device__ __forceinline__ unsigned long long packkey(float s, int i) {
    unsigned u = __builtin_bit_cast(unsigned, s);
    u = (u & 0x80000000u) ? ~u : (u | 0x80000000u);
    return ((unsigned long long)u << 32) | (unsigned)(0xFFFFFFFFu - (unsigned)i);
}

__global__ __launch_bounds__(256)
void rank_topk(const float* __restrict__ score, int n, int k,
               int* __restrict__ perm, float* __restrict__ vals,
               int* __restrict__ inv)
{
    __shared__ unsigned long long sk[1024];
    int i = blockIdx.x * 256 + threadIdx.x;
    float s = score[i];
    unsigned long long mykey = packkey(s, i);
    int rank = 0;
    for (int jt = 0; jt < n; jt += 1024) {
#pragma unroll
        for (int q = 0; q < 4; q++) {
            int idx = jt + threadIdx.x + q * 256;
            sk[threadIdx.x + q * 256] = packkey(score[idx], idx);
        }
        __syncthreads();
#pragma unroll 16
        for (int q = 0; q < 1024; q++) rank += (sk[q] > mykey) ? 1 : 0;
        __syncthreads();
    }
    if (rank < k) { perm[rank] = i; vals[rank] = s; }
    inv[i] = (rank < k) ? rank : -1;
}

// gathered+scaled x -> hi/lo  (x4 vectorized)
__global__ void gather_x_hl(const float* __restrict__ xold,
                            const int* __restrict__ perm,
                            const float* __restrict__ vals,
                            short* __restrict__ Xh, short* __restrict__ Xl, int C)
{
    int t4 = (blockIdx.x * 256 + threadIdx.x) * 4;
    int r = t4 / C, c = t4 - r * C;
    float vv = vals[r];
    f32x4 x = *(const f32x4*)&xold[(size_t)perm[r] * C + c];
    s16x4 hh, ll;
#pragma unroll
    for (int q = 0; q < 4; q++) {
        float v = x[q] * vv;
        short h = f2bf(v);
        hh[q] = h; ll[q] = f2bf(v - bf2f(h));
    }
    *(s16x4*)&Xh[t4] = hh;
    *(s16x4*)&Xl[t4] = ll;
}

// G = (A+I)[perm,:] from bf16 A (small-int exact); zeroes rs_next  (x8 vec)
__global__ void gatherG_h(const short* __restrict__ A, int n,
                          const int* __restrict__ perm,
                          short* __restrict__ Gh, int kk,
                          float* __restrict__ rsz)
{
    int idx = blockIdx.x * 256 + threadIdx.x;
    if (idx < kk) rsz[idx] = 0.f;
    int t8 = idx * 8;
    if (t8 >= kk * n) return;
    int r = t8 / n, c0 = t8 - r * n;
    int pr = perm[r];
    bf16x8 a = *(const bf16x8*)&A[(size_t)pr * n + c0];
    if (pr >= c0 && pr < c0 + 8)
        a[pr - c0] = f2bf(bf2f(a[pr - c0]) + 1.f);
    *(bf16x8*)&Gh[t8] = a;
}

__global__ void gatherG_hl(const short* __restrict__ Ahi, const short* __restrict__ Alo,
                           int n, const int* __restrict__ perm,
                           short* __restrict__ Gh, short* __restrict__ Gl, int kk,
                           float* __restrict__ rsz)
{
    int idx = blockIdx.x * 256 + threadIdx.x;
    if (idx < kk) rsz[idx] = 0.f;
    int t8 = idx * 8;
    if (t8 >= kk * n) return;
    int r = t8 / n, c0 = t8 - r * n;
    int pr = perm[r];
    bf16x8 ah = *(const bf16x8*)&Ahi[(size_t)pr * n + c0];
    bf16x8 al = *(const bf16x8*)&Alo[(size_t)pr * n + c0];
    bf16x8 gh, gl;
#pragma unroll
    for (int q = 0; q < 8; q++) {
        float v = bf2f(ah[q]) + bf2f(al[q]) + ((c0 + q == pr) ? 1.f : 0.f);
        short h = f2bf(v);
        gh[q] = h; gl[q] = f2bf(v - bf2f(h));
    }
    *(bf16x8*)&Gh[t8] = gh;
    *(bf16x8*)&Gl[t8] = gl;
}

// fp32 mirrored slices -> A hi(/lo), rowsums  (x4 vectorized)
template<bool LO>
__global__ void aug_finish_f(const float* __restrict__ Cp, int S, int kk,
                             short* __restrict__ Ahs, short* __restrict__ Als,
                             float* __restrict__ rs)
{
    int t4 = (blockIdx.x * 256 + threadIdx.x) * 4;
    int r = t4 / kk, c0 = t4 - r * kk;
    size_t stride = (size_t)kk * kk;
    f32x4 v = {0.f, 0.f, 0.f, 0.f};
    for (int s = 0; s < S; s++) v += *(const f32x4*)&Cp[t4 + s * stride];
    if (r >= c0 && r < c0 + 4) v[r - c0] = 0.f;
    s16x4 hh, ll;
    float ws = 0.f;
#pragma unroll
    for (int q = 0; q < 4; q++) {
        short h = f2bf(v[q]);
        hh[q] = h;
        if (LO) ll[q] = f2bf(v[q] - bf2f(h));
        ws += v[q];
    }
    *(s16x4*)&Ahs[t4] = hh;
    if (LO) *(s16x4*)&Als[t4] = ll;
    for (int off = 32; off; off >>= 1) ws += __shfl_down(ws, off);
    if ((threadIdx.x & 63) == 0) atomicAdd(&rs[r], ws);
}

// ---------------------------------------------------------------------------
// Host orchestration
// ---------------------------------------------------------------------------

extern "C" void kernel_launch(void* const* d_in, const int* in_sizes, int n_in,
                              void* d_out, int out_size, void* d_ws, size_t ws_size,
                              hipStream_t stream)
{
    const float* x0  = (const float*)d_in[0];
    const int*   ei  = (const int*)d_in[1];
    const float* Wd0 = (const float*)d_in[2];  const float* bd0 = (const float*)d_in[3];
    const float* Wd1 = (const float*)d_in[4];  const float* bd1 = (const float*)d_in[5];
    const float* Wd2 = (const float*)d_in[6];  const float* bd2 = (const float*)d_in[7];
    const float* Wd3 = (const float*)d_in[8];  const float* bd3 = (const float*)d_in[9];
    const float* p1  = (const float*)d_in[10];
    const float* p2  = (const float*)d_in[11];
    const float* p3  = (const float*)d_in[12];
    const float* Wu0 = (const float*)d_in[13]; const float* bu0 = (const float*)d_in[14];
    const float* Wu1 = (const float*)d_in[15]; const float* bu1 = (const float*)d_in[16];
    const float* Wu2 = (const float*)d_in[17]; const float* bu2 = (const float*)d_in[18];

    const int E = in_sizes[1] / 2;

    char* ws = (char*)d_ws;
    size_t off = 0;
    auto alloc = [&](size_t bytes) -> void* {
        void* p = ws + off;
        off += (bytes + 255) & ~(size_t)255;
        return p;
    };
    short* A0h  = (short*)alloc((size_t)4096 * 4096 * 2);
    short* A1h  = (short*)alloc((size_t)2048 * 2048 * 2);
    short* A2h  = (short*)alloc((size_t)1024 * 1024 * 2);
    short* A2l  = (short*)alloc((size_t)1024 * 1024 * 2);
    short* A3h  = (short*)alloc((size_t)512 * 512 * 2);
    short* A3l  = (short*)alloc((size_t)512 * 512 * 2);
    short* Gh   = (short*)alloc((size_t)1024 * 2048 * 2);
    short* Gl   = (short*)alloc((size_t)512 * 1024 * 2);
    int*   csr  = (int*)alloc((size_t)4096 * 128 * 4);
    unsigned long long* maskb = (unsigned long long*)alloc((size_t)2048 * 64 * 8);
    float* Zf   = (float*)alloc((size_t)4096 * 256 * 4);
    float* Cp   = (float*)alloc((size_t)64 * 1024 * 1024);   // partial arena
    float* xs0  = (float*)alloc((size_t)4096 * 256 * 4);
    float* xs1  = (float*)alloc((size_t)2048 * 256 * 4);
    float* xs2  = (float*)alloc((size_t)1024 * 256 * 4);
    float* xu0  = (float*)alloc((size_t)4096 * 256 * 4);
    float* xu1  = (float*)alloc((size_t)2048 * 256 * 4);
    float* xu2  = (float*)alloc((size_t)1024 * 256 * 4);
    short* xu0h = (short*)alloc((size_t)4096 * 256 * 2);
    short* xu0l = (short*)alloc((size_t)4096 * 256 * 2);
    short* xu1h = (short*)alloc((size_t)2048 * 256 * 2);
    short* xu1l = (short*)alloc((size_t)2048 * 256 * 2);
    short* xu2h = (short*)alloc((size_t)1024 * 256 * 2);
    short* xu2l = (short*)alloc((size_t)1024 * 256 * 2);
    short* X0h  = (short*)alloc((size_t)4096 * 128 * 2);
    short* X0l  = (short*)alloc((size_t)4096 * 128 * 2);
    short* xah  = (short*)alloc((size_t)2048 * 256 * 2);
    short* xal  = (short*)alloc((size_t)2048 * 256 * 2);
    short* Wth  = (short*)alloc((size_t)393216 * 2);
    short* Wtl  = (short*)alloc((size_t)393216 * 2);
    short* Zh   = (short*)alloc((size_t)256 * 4096 * 2);
    short* Zl   = (short*)alloc((size_t)256 * 4096 * 2);
    float* rs0  = (float*)alloc(4096 * 4);
    float* rs1  = (float*)alloc(2048 * 4);
    float* rs2  = (float*)alloc(1024 * 4);
    float* rs3  = (float*)alloc(512 * 4);
    float* scoreb = (float*)alloc(4096 * 4);
    float* valsb  = (float*)alloc(2048 * 4);
    int*   perm1  = (int*)alloc(2048 * 4);
    int*   perm2  = (int*)alloc(1024 * 4);
    int*   perm3  = (int*)alloc(512 * 4);
    int*   inv1   = (int*)alloc(4096 * 4);
    int*   inv2   = (int*)alloc(2048 * 4);
    int*   inv3   = (int*)alloc(1024 * 4);

    // dense-A GCN layer (levels 1..3): EPI3 xw -> z_reduce -> AZ -> gcn_final
    auto gcn_dense = [&](const short* Xh, const short* Xl, int n, int Kc, int Cout,
                         const short* pAh, const short* pAl, const float* rsA,
                         int wtoff, const float* b,
                         float* out, short* oh, short* ol, int relu, int modeA,
                         int Saz, const int* inv, const float* res, int nout) {
        int Sxw = 4;
        gemm_bt<2, 3><<<dim3(Cout / 128, n / 128, Sxw), 256, 0, stream>>>(
            Xh, Xl, Wth + wtoff, Wtl + wtoff, Cp, n, Cout, Kc, Kc / Sxw);
        z_reduce<<<(n * Cout) / 1024, 256, 0, stream>>>(Cp, Sxw, rsA, Zh, Zl, n, Cout);
        dim3 g(Cout / 128, n / 128, Saz);
        if (modeA == 1)
            gemm_bt<1, 0><<<g, 256, 0, stream>>>(pAh, nullptr, Zh, Zl, Cp, n, Cout, n, n / Saz);
        else
            gemm_bt<2, 0><<<g, 256, 0, stream>>>(pAh, pAl, Zh, Zl, Cp, n, Cout, n, n / Saz);
        gcn_final<<<(nout * Cout) / 1024, 256, 0, stream>>>(
            Cp, Saz, Zh, Zl, rsA, b, out, oh, ol, n, Cout, relu, inv, res);
    };

    auto pool = [&](const float* xlev, int n, const float* p, int* perm, int* inv) {
        int k = n / 2;
        score_kernel<<<n / 4, 256, 0, stream>>>(xlev, p, scoreb, n);
        rank_topk<<<n / 256, 256, 0, stream>>>(scoreb, n, k, perm, valsb, inv);
        gather_x_hl<<<k / 4, 256, 0, stream>>>(xlev, perm, valsb, xah, xal, 256);
    };

    // ---- prep + adjacency + CSR ----
    prep<<<3584, 256, 0, stream>>>(Wd0, Wd1, Wd2, Wd3, Wu0, Wu1, Wu2, x0,
                                   Wth, Wtl, X0h, X0l);
    hipMemsetAsync(A0h, 0, (size_t)4096 * 4096 * 2, stream);
    build_adj_bf16<<<(E + 255) / 256, 256, 0, stream>>>(ei, E, A0h, 4096);
    row_compact<<<1024, 256, 0, stream>>>(A0h, 4096, csr, rs0);

    // ---- down 0 (A0 sparse): x@W -> Zf -> SpMM+epilogue ----
    gemm_bt<2, 0><<<dim3(2, 32, 4), 256, 0, stream>>>(
        X0h, X0l, Wth, Wtl, Cp, 4096, 256, 128, 32);
    zf_reduce<<<1024, 256, 0, stream>>>(Cp, 4, rs0, Zf, 4096, 256);
    spmm_gcn<256, 1><<<1024, 256, 0, stream>>>(csr, rs0, Zf, bd0, xs0);

    // ---- level 0 -> 1: pool + split-K bitset popcount augment ----
    pool(xs0, 4096, p1, perm1, inv1);
    build_mask<<<512, 256, 0, stream>>>(csr, rs0, perm1, maskb, rs1);
    popc_aug_p<<<dim3(32, 32, 4), 256, 0, stream>>>(maskb, (short*)Cp);
    aug_merge<<<dim3(32, 32), 256, 0, stream>>>((const short*)Cp, 2048, A1h, rs1);
    gcn_dense(xah, xal, 2048, 256, 256, A1h, nullptr, rs1, 32768, bd1,
              xs1, nullptr, nullptr, 1, 1, 16, nullptr, nullptr, 2048);

    // ---- level 1 -> 2 (dense TRI) ----
    pool(xs1, 2048, p2, perm2, inv2);
    gatherG_h<<<(1024 * 2048 / 8) / 256, 256, 0, stream>>>(A1h, 2048, perm2, Gh, 1024, rs2);
    gemm_bt<0, 1><<<dim3(8, 8, 8), 256, 0, stream>>>(Gh, nullptr, Gh, nullptr, Cp, 1024, 1024, 2048, 256);
    aug_finish_f<true><<<(1024 * 1024 / 4) / 256, 256, 0, stream>>>(Cp, 8, 1024, A2h, A2l, rs2);
    gcn_dense(xah, xal, 1024, 256, 256, A2h, A2l, rs2, 98304, bd2,
              xs2, nullptr, nullptr, 1, 2, 8, nullptr, nullptr, 1024);

    // ---- level 2 -> 3 (dense TRI) ----
    pool(xs2, 1024, p3, perm3, inv3);
    gatherG_hl<<<(512 * 1024 / 8) / 256, 256, 0, stream>>>(A2h, A2l, 1024, perm3, Gh, Gl, 512, rs3);
    gemm_bt<2, 1><<<dim3(4, 4, 8), 256, 0, stream>>>(Gh, Gl, Gh, Gl, Cp, 512, 512, 1024, 128);
    aug_finish_f<true><<<(512 * 512 / 4) / 256, 256, 0, stream>>>(Cp, 8, 512, A3h, A3l, rs3);

    // ---- down 3: out scattered into xu2 = xs2 + u (inv3) ----
    gcn_dense(xah, xal, 512, 256, 256, A3h, A3l, rs3, 163840, bd3,
              xu2, xu2h, xu2l, 1, 2, 8, inv3, xs2, 1024);

    // ---- up 0: out scattered into xu1 = xs1 + u (inv2) ----
    gcn_dense(xu2h, xu2l, 1024, 256, 256, A2h, A2l, rs2, 229376, bu0,
              xu1, xu1h, xu1l, 1, 2, 8, inv2, xs1, 2048);

    // ---- up 1: out scattered into xu0 = xs0 + u (inv1) ----
    gcn_dense(xu1h, xu1l, 2048, 256, 256, A1h, nullptr, rs1, 294912, bu1,
              xu0, xu0h, xu0l, 1, 1, 16, inv1, xs0, 4096);

    // ---- up 2 (A0 sparse, Cout=128, no relu) -> d_out ----
    gemm_bt<2, 0><<<dim3(1, 32, 8), 256, 0, stream>>>(
        xu0h, xu0l, Wth + 360448, Wtl + 360448, Cp, 4096, 128, 256, 32);
    zf_reduce<<<512, 256, 0, stream>>>(Cp, 8, rs0, Zf, 4096, 128);
    spmm_gcn<128, 0><<<1024, 256, 0, stream>>>(csr, rs0, Zf, bu2, (float*)d_out);
}

// Round 13
// 466.291 us; speedup vs baseline: 1.1727x; 1.1265x over previous
//
#include <hip/hip_runtime.h>

// ---------------------------------------------------------------------------
// GraphUNet on MI355X.  Round-13: rank-topk parallelized — rank_count over a
// 2D (i-chunk, j-chunk) grid with per-i atomic partial ranks (the r3-r12
// version ran n/256 blocks = 16 blocks at n=4096, 0.6% occupancy, 46 us);
// rank_final emits perm/vals/inv.  Rest identical to round 12.
// ---------------------------------------------------------------------------

typedef __attribute__((ext_vector_type(8))) short bf16x8;
typedef __attribute__((ext_vector_type(4))) short s16x4;
typedef __attribute__((ext_vector_type(4))) float f32x4;

__device__ __forceinline__ short f2bf(float f) {
    unsigned u = __builtin_bit_cast(unsigned, f);
    u += 0x7FFFu + ((u >> 16) & 1u);          // RNE
    return (short)(u >> 16);
}
__device__ __forceinline__ float bf2f(short s) {
    unsigned u = ((unsigned)(unsigned short)s) << 16;
    return __builtin_bit_cast(float, u);
}

#define GLL16(gsrc, ldst)                                                        \
    __builtin_amdgcn_global_load_lds(                                            \
        (__attribute__((address_space(1))) void*)(gsrc),                         \
        (__attribute__((address_space(3))) void*)(ldst), 16, 0, 0)

// ---------------------------------------------------------------------------
// bf16 BT GEMM: C(MxN) = A(MxK) @ B^T, B stored N x K row-major.
// MODE 0: Ah@Bh ; 1: +Ah@Bl ; 2: +Al@Bh   (lo*lo dropped, ~2^-18 rel)
// EPI 0: fp32 partial slice [z][M][N]
// EPI 1: fp32 mirrored square slices (TRI: blocks by>bx exit)
// EPI 3: fp32 TRANSPOSED partial slice [z][N][M] (f32x4 stores)
// ---------------------------------------------------------------------------
template<int MODE, int EPI>
__global__ __launch_bounds__(256, 2)
void gemm_bt(const short* __restrict__ Ah, const short* __restrict__ Al,
             const short* __restrict__ Bh, const short* __restrict__ Bl,
             float* __restrict__ Cf, int M, int N, int K, int kChunk)
{
    if (EPI == 1 && (int)blockIdx.y > (int)blockIdx.x) return;

    __shared__ short sAh[128 * 32];
    __shared__ short sBh[128 * 32];
    __shared__ short sAl[(MODE == 2) ? 128 * 32 : 8];
    __shared__ short sBl[(MODE >= 1) ? 128 * 32 : 8];

    const int t    = threadIdx.x;
    const int lane = t & 63;
    const int wave = t >> 6;
    const int tM   = blockIdx.y * 128;
    const int tN   = blockIdx.x * 128;
    const int k0   = blockIdx.z * kChunk;

    const int wm  = (wave >> 1) * 64;
    const int wn  = (wave & 1) * 64;
    const int l15 = lane & 15;
    const int g8  = (lane >> 4) * 8;

    f32x4 acc[4][4];
    const f32x4 zero = {0.f, 0.f, 0.f, 0.f};
#pragma unroll
    for (int i = 0; i < 4; i++)
#pragma unroll
        for (int j = 0; j < 4; j++) acc[i][j] = zero;

    const int i0 = t, i1 = t + 256;
    const short* a0 = Ah + (size_t)(tM + (i0 >> 2)) * K + (i0 & 3) * 8;
    const short* a1 = Ah + (size_t)(tM + (i1 >> 2)) * K + (i1 & 3) * 8;
    const short* b0 = Bh + (size_t)(tN + (i0 >> 2)) * K + (i0 & 3) * 8;
    const short* b1 = Bh + (size_t)(tN + (i1 >> 2)) * K + (i1 & 3) * 8;
    const short *bl0 = nullptr, *bl1 = nullptr, *al0 = nullptr, *al1 = nullptr;
    if (MODE >= 1) {
        bl0 = Bl + (size_t)(tN + (i0 >> 2)) * K + (i0 & 3) * 8;
        bl1 = Bl + (size_t)(tN + (i1 >> 2)) * K + (i1 & 3) * 8;
    }
    if (MODE == 2) {
        al0 = Al + (size_t)(tM + (i0 >> 2)) * K + (i0 & 3) * 8;
        al1 = Al + (size_t)(tM + (i1 >> 2)) * K + (i1 & 3) * 8;
    }

    for (int kb = k0; kb < k0 + kChunk; kb += 32) {
        GLL16(a0 + kb, &sAh[i0 * 8]);
        GLL16(a1 + kb, &sAh[i1 * 8]);
        GLL16(b0 + kb, &sBh[i0 * 8]);
        GLL16(b1 + kb, &sBh[i1 * 8]);
        if (MODE >= 1) { GLL16(bl0 + kb, &sBl[i0 * 8]); GLL16(bl1 + kb, &sBl[i1 * 8]); }
        if (MODE == 2) { GLL16(al0 + kb, &sAl[i0 * 8]); GLL16(al1 + kb, &sAl[i1 * 8]); }
        __syncthreads();

        bf16x8 aF[4], bF[4], aL[4], bL[4];
#pragma unroll
        for (int i = 0; i < 4; i++)
            aF[i] = *(const bf16x8*)&sAh[(wm + i * 16 + l15) * 32 + g8];
#pragma unroll
        for (int j = 0; j < 4; j++)
            bF[j] = *(const bf16x8*)&sBh[(wn + j * 16 + l15) * 32 + g8];
        if (MODE >= 1)
#pragma unroll
            for (int j = 0; j < 4; j++)
                bL[j] = *(const bf16x8*)&sBl[(wn + j * 16 + l15) * 32 + g8];
        if (MODE == 2)
#pragma unroll
            for (int i = 0; i < 4; i++)
                aL[i] = *(const bf16x8*)&sAl[(wm + i * 16 + l15) * 32 + g8];

#pragma unroll
        for (int i = 0; i < 4; i++)
#pragma unroll
            for (int j = 0; j < 4; j++) {
                acc[i][j] = __builtin_amdgcn_mfma_f32_16x16x32_bf16(aF[i], bF[j], acc[i][j], 0, 0, 0);
                if (MODE >= 1)
                    acc[i][j] = __builtin_amdgcn_mfma_f32_16x16x32_bf16(aF[i], bL[j], acc[i][j], 0, 0, 0);
                if (MODE == 2)
                    acc[i][j] = __builtin_amdgcn_mfma_f32_16x16x32_bf16(aL[i], bF[j], acc[i][j], 0, 0, 0);
            }
        __syncthreads();
    }

    // C/D layout: col=lane&15, row=(lane>>4)*4+reg  [m89-verified]
    const int r4 = (lane >> 4) * 4;
    if (EPI == 3) {
        float* CT = Cf + (size_t)blockIdx.z * M * N;   // [N][M]
#pragma unroll
        for (int i = 0; i < 4; i++)
#pragma unroll
            for (int j = 0; j < 4; j++) {
                const int col   = tN + wn + j * 16 + l15;
                const int rbase = tM + wm + i * 16 + r4;
                *(f32x4*)&CT[(size_t)col * M + rbase] = acc[i][j];
            }
    } else {
        float* Cg = Cf + (size_t)blockIdx.z * M * N;
#pragma unroll
        for (int i = 0; i < 4; i++)
#pragma unroll
            for (int j = 0; j < 4; j++) {
                const int col = tN + wn + j * 16 + l15;
                float* cp = Cg + (size_t)(tM + wm + i * 16 + r4) * N + col;
#pragma unroll
                for (int r = 0; r < 4; r++) cp[(size_t)r * N] = acc[i][j][r];
            }
        if (EPI == 1 && tM != tN) {
#pragma unroll
            for (int i = 0; i < 4; i++)
#pragma unroll
                for (int j = 0; j < 4; j++) {
                    const int col   = tN + wn + j * 16 + l15;
                    const int rbase = tM + wm + i * 16 + r4;
                    *(f32x4*)&Cg[(size_t)col * N + rbase] = acc[i][j];
                }
        }
    }
}

// ---------------------------------------------------------------------------
// Utility kernels
// ---------------------------------------------------------------------------

// one-shot prep: W^T hi/lo for all 7 layers + x0 hi/lo split
__global__ void prep(const float* __restrict__ Wd0, const float* __restrict__ Wd1,
                     const float* __restrict__ Wd2, const float* __restrict__ Wd3,
                     const float* __restrict__ Wu0, const float* __restrict__ Wu1,
                     const float* __restrict__ Wu2, const float* __restrict__ x0,
                     short* __restrict__ Wth, short* __restrict__ Wtl,
                     short* __restrict__ Xh, short* __restrict__ Xl)
{
    int t = blockIdx.x * 256 + threadIdx.x;
    float v; int dst;
    if (t < 32768)       { int e = t;          v = Wd0[e]; dst = 0      + (e & 255) * 128 + (e >> 8); }
    else if (t < 98304)  { int e = t - 32768;  v = Wd1[e]; dst = 32768  + (e & 255) * 256 + (e >> 8); }
    else if (t < 163840) { int e = t - 98304;  v = Wd2[e]; dst = 98304  + (e & 255) * 256 + (e >> 8); }
    else if (t < 229376) { int e = t - 163840; v = Wd3[e]; dst = 163840 + (e & 255) * 256 + (e >> 8); }
    else if (t < 294912) { int e = t - 229376; v = Wu0[e]; dst = 229376 + (e & 255) * 256 + (e >> 8); }
    else if (t < 360448) { int e = t - 294912; v = Wu1[e]; dst = 294912 + (e & 255) * 256 + (e >> 8); }
    else if (t < 393216) { int e = t - 360448; v = Wu2[e]; dst = 360448 + (e & 127) * 256 + (e >> 7); }
    else {
        int e = t - 393216;                      // x0: 4096*128
        v = x0[e];
        short h = f2bf(v);
        Xh[e] = h; Xl[e] = f2bf(v - bf2f(h));
        return;
    }
    short h = f2bf(v);
    Wth[dst] = h; Wtl[dst] = f2bf(v - bf2f(h));
}

__global__ void build_adj_bf16(const int* __restrict__ ei, int E,
                               short* __restrict__ A, int n)
{
    int e = blockIdx.x * 256 + threadIdx.x;
    if (e >= E) return;
    int i = ei[e], j = ei[E + e];
    if (i != j) {
        A[(size_t)i * n + j] = (short)0x3F80;
        A[(size_t)j * n + i] = (short)0x3F80;
    }
}

// dense bf16 A -> CSR (<=128 nnz/row, ascending) + degree (== rowsum, exact)
__global__ void row_compact(const short* __restrict__ A, int n,
                            int* __restrict__ csr, float* __restrict__ rs)
{
    int row = blockIdx.x * 4 + (threadIdx.x >> 6);
    int lane = threadIdx.x & 63;
    const short* ar = A + (size_t)row * n;
    int* out = csr + (size_t)row * 128;
    int base = 0;
    for (int c0 = 0; c0 < n; c0 += 64) {
        short v = ar[c0 + lane];
        unsigned long long mask = __ballot(v != 0);
        if (v != 0) {
            int pos = base + __popcll(mask & ((1ull << lane) - 1ull));
            if (pos < 128) out[pos] = c0 + lane;
        }
        base += __popcll(mask);
    }
    if (lane == 0) rs[row] = (float)base;
}

// build 4096-bit neighborhood+self masks for selected rows; zero rs
__global__ void build_mask(const int* __restrict__ csr, const float* __restrict__ deg,
                           const int* __restrict__ perm,
                           unsigned long long* __restrict__ mask,
                           float* __restrict__ rs)
{
    __shared__ unsigned long long m[4][64];
    int wave = threadIdx.x >> 6, lane = threadIdx.x & 63;
    int r = blockIdx.x * 4 + wave;
    int u = perm[r];
    m[wave][lane] = 0ull;
    __syncthreads();
    int dg = (int)deg[u];
    const int* nb = csr + (size_t)u * 128;
    for (int q = lane; q < dg; q += 64) {
        int c = nb[q];
        atomicOr(&m[wave][c >> 6], 1ull << (c & 63));
    }
    if (lane == 0) {
        atomicOr(&m[wave][u >> 6], 1ull << (u & 63));
        rs[r] = 0.f;
    }
    __syncthreads();
    mask[(size_t)r * 64 + lane] = m[wave][lane];
}

// popcount partial: slice z covers words [z*16, z*16+16).  64x64 TRI tiles,
// 18 KB LDS -> 8 blocks/CU.  int16 partial tile at Cp[(z*1024 + by*32+bx)*4096].
#define PSTR2 18
__global__ __launch_bounds__(256, 8)
void popc_aug_p(const unsigned long long* __restrict__ mask,
                short* __restrict__ Cp)
{
    const int bx = blockIdx.x, by = blockIdx.y, z = blockIdx.z;
    if (by > bx) return;
    __shared__ unsigned long long a[64 * PSTR2];
    __shared__ unsigned long long b[64 * PSTR2];
    const int t = threadIdx.x;
#pragma unroll
    for (int p = 0; p < 4; p++) {
        int idx = p * 256 + t;           // 0..1023 = rr*16 + w
        int rr = idx >> 4, w = idx & 15;
        a[rr * PSTR2 + w] = mask[((size_t)(by * 64 + rr)) * 64 + z * 16 + w];
        b[rr * PSTR2 + w] = mask[((size_t)(bx * 64 + rr)) * 64 + z * 16 + w];
    }
    __syncthreads();
    const int i0 = (t >> 4) * 4;         // 4 consecutive rows
    const int j0 = t & 15;               // cols j0 + 16*qj
    int acc[4][4];
#pragma unroll
    for (int qi = 0; qi < 4; qi++)
#pragma unroll
        for (int qj = 0; qj < 4; qj++) acc[qi][qj] = 0;
#pragma unroll
    for (int w = 0; w < 16; w += 2) {
        ulong2 av[4], bv[4];
#pragma unroll
        for (int q = 0; q < 4; q++) av[q] = *(const ulong2*)&a[(i0 + q) * PSTR2 + w];
#pragma unroll
        for (int q = 0; q < 4; q++) bv[q] = *(const ulong2*)&b[(j0 + 16 * q) * PSTR2 + w];
#pragma unroll
        for (int qi = 0; qi < 4; qi++)
#pragma unroll
            for (int qj = 0; qj < 4; qj++) {
                acc[qi][qj] += __builtin_popcountll(av[qi].x & bv[qj].x);
                acc[qi][qj] += __builtin_popcountll(av[qi].y & bv[qj].y);
            }
    }
    short* out = Cp + ((size_t)z * 1024 + (size_t)(by * 32 + bx)) * 4096;
#pragma unroll
    for (int qi = 0; qi < 4; qi++)
#pragma unroll
        for (int qj = 0; qj < 4; qj++)
            out[(i0 + qi) * 64 + j0 + 16 * qj] = (short)acc[qi][qj];
}

// merge 4 int16 slices -> A1h (bf16, diag 0) + LDS-transposed mirror + rowsums
__global__ __launch_bounds__(256)
void aug_merge(const short* __restrict__ Cp, int kk,
               short* __restrict__ Ahs, float* __restrict__ rs)
{
    const int bx = blockIdx.x, by = blockIdx.y;
    if (by > bx) return;
    __shared__ float tile[64][65];
    __shared__ float rsum[64], csum[64];
    const int t = threadIdx.x;
    const int i  = t >> 2;               // row 0..63
    const int c0 = (t & 3) * 16;         // 16 consecutive cols
    const size_t tb = (size_t)(by * 32 + bx) * 4096;
    const size_t ss = (size_t)1024 * 4096;
    if (t < 64) { rsum[t] = 0.f; csum[t] = 0.f; }

    int v[16];
#pragma unroll
    for (int q = 0; q < 16; q++) v[q] = 0;
    for (int s = 0; s < 4; s++) {
        bf16x8 p0 = *(const bf16x8*)&Cp[tb + s * ss + i * 64 + c0];
        bf16x8 p1 = *(const bf16x8*)&Cp[tb + s * ss + i * 64 + c0 + 8];
#pragma unroll
        for (int q = 0; q < 8; q++) { v[q] += (int)p0[q]; v[8 + q] += (int)p1[q]; }
    }
    const int gi = by * 64 + i;
    float rp = 0.f;
    s16x4 pk[4];
#pragma unroll
    for (int q = 0; q < 16; q++) {
        const int gj = bx * 64 + c0 + q;
        float val = (gi == gj) ? 0.f : (float)v[q];
        tile[i][c0 + q] = val;
        rp += val;
        pk[q >> 2][q & 3] = f2bf(val);
    }
#pragma unroll
    for (int q = 0; q < 4; q++)
        *(s16x4*)&Ahs[(size_t)gi * kk + bx * 64 + c0 + q * 4] = pk[q];
    __syncthreads();
    atomicAdd(&rsum[i], rp);
    if (bx != by) {
        float cpv = 0.f;
#pragma unroll
        for (int q = 0; q < 16; q++) {
            float val = tile[c0 + q][i];
            cpv += val;
            pk[q >> 2][q & 3] = f2bf(val);
        }
#pragma unroll
        for (int q = 0; q < 4; q++)
            *(s16x4*)&Ahs[(size_t)(bx * 64 + i) * kk + by * 64 + c0 + q * 4] = pk[q];
        atomicAdd(&csum[i], cpv);
    }
    __syncthreads();
    if (t < 64) {
        atomicAdd(&rs[by * 64 + t], rsum[t]);
        if (bx != by) atomicAdd(&rs[bx * 64 + t], csum[t]);
    }
}

// reduce transposed xw partial slices -> Z^T hi/lo  (x4 vectorized)
__global__ void z_reduce(const float* __restrict__ Cp, int S,
                         const float* __restrict__ rs,
                         short* __restrict__ Zh, short* __restrict__ Zl,
                         int n, int C)
{
    int t4 = (blockIdx.x * 256 + threadIdx.x) * 4;   // t = c*n + r layout
    int r = t4 % n;
    size_t stride = (size_t)n * C;
    f32x4 v = {0.f, 0.f, 0.f, 0.f};
    for (int s = 0; s < S; s++) v += *(const f32x4*)&Cp[t4 + s * stride];
    f32x4 rsv = *(const f32x4*)&rs[r];
    s16x4 zh, zl;
#pragma unroll
    for (int q = 0; q < 4; q++) {
        float z = v[q] / sqrtf(rsv[q] + 2.f);
        short h = f2bf(z);
        zh[q] = h; zl[q] = f2bf(z - bf2f(h));
    }
    *(s16x4*)&Zh[t4] = zh;
    *(s16x4*)&Zl[t4] = zl;
}

// reduce row-major xw partial slices -> Zf fp32 [r][C]  (x4 vectorized)
__global__ void zf_reduce(const float* __restrict__ Cp, int S,
                          const float* __restrict__ rs,
                          float* __restrict__ Zf, int n, int C)
{
    int t4 = (blockIdx.x * 256 + threadIdx.x) * 4;   // t = r*C + c
    int r = t4 / C;
    size_t stride = (size_t)n * C;
    f32x4 v = {0.f, 0.f, 0.f, 0.f};
    for (int s = 0; s < S; s++) v += *(const f32x4*)&Cp[t4 + s * stride];
    float d = 1.f / sqrtf(rs[r] + 2.f);
    v *= d;
    *(f32x4*)&Zf[t4] = v;
}

// CSR SpMM + fused GCN epilogue
template<int CN, int RELU>
__global__ __launch_bounds__(256)
void spmm_gcn(const int* __restrict__ csr, const float* __restrict__ rs,
              const float* __restrict__ Zf, const float* __restrict__ b,
              float* __restrict__ out)
{
    const int lane = threadIdx.x & 63;
    const int row  = blockIdx.x * 4 + (threadIdx.x >> 6);
    const int dg   = (int)rs[row];
    const int* nb  = csr + (size_t)row * 128;
    if (CN == 256) {
        const int c = lane * 4;
        float4 acc = {0.f, 0.f, 0.f, 0.f};
        int q = 0;
        for (; q + 4 <= dg; q += 4) {
            int j0 = nb[q], j1 = nb[q+1], j2 = nb[q+2], j3 = nb[q+3];
            float4 z0 = *(const float4*)&Zf[(size_t)j0 * CN + c];
            float4 z1 = *(const float4*)&Zf[(size_t)j1 * CN + c];
            float4 z2 = *(const float4*)&Zf[(size_t)j2 * CN + c];
            float4 z3 = *(const float4*)&Zf[(size_t)j3 * CN + c];
            acc.x += z0.x; acc.y += z0.y; acc.z += z0.z; acc.w += z0.w;
            acc.x += z1.x; acc.y += z1.y; acc.z += z1.z; acc.w += z1.w;
            acc.x += z2.x; acc.y += z2.y; acc.z += z2.z; acc.w += z2.w;
            acc.x += z3.x; acc.y += z3.y; acc.z += z3.z; acc.w += z3.w;
        }
        for (; q < dg; q++) {
            float4 z = *(const float4*)&Zf[(size_t)nb[q] * CN + c];
            acc.x += z.x; acc.y += z.y; acc.z += z.z; acc.w += z.w;
        }
        float d = 1.f / sqrtf(rs[row] + 2.f);
        float4 zi = *(const float4*)&Zf[(size_t)row * CN + c];
        float4 bb = *(const float4*)&b[c];
        float4 g;
        g.x = d * acc.x + 2.f * d * zi.x + bb.x;
        g.y = d * acc.y + 2.f * d * zi.y + bb.y;
        g.z = d * acc.z + 2.f * d * zi.z + bb.z;
        g.w = d * acc.w + 2.f * d * zi.w + bb.w;
        if (RELU) {
            g.x = fmaxf(g.x, 0.f); g.y = fmaxf(g.y, 0.f);
            g.z = fmaxf(g.z, 0.f); g.w = fmaxf(g.w, 0.f);
        }
        *(float4*)&out[(size_t)row * CN + c] = g;
    } else {
        const int c = lane * 2;
        float2 acc = {0.f, 0.f};
        int q = 0;
        for (; q + 4 <= dg; q += 4) {
            int j0 = nb[q], j1 = nb[q+1], j2 = nb[q+2], j3 = nb[q+3];
            float2 z0 = *(const float2*)&Zf[(size_t)j0 * CN + c];
            float2 z1 = *(const float2*)&Zf[(size_t)j1 * CN + c];
            float2 z2 = *(const float2*)&Zf[(size_t)j2 * CN + c];
            float2 z3 = *(const float2*)&Zf[(size_t)j3 * CN + c];
            acc.x += z0.x; acc.y += z0.y;
            acc.x += z1.x; acc.y += z1.y;
            acc.x += z2.x; acc.y += z2.y;
            acc.x += z3.x; acc.y += z3.y;
        }
        for (; q < dg; q++) {
            float2 z = *(const float2*)&Zf[(size_t)nb[q] * CN + c];
            acc.x += z.x; acc.y += z.y;
        }
        float d = 1.f / sqrtf(rs[row] + 2.f);
        float2 zi = *(const float2*)&Zf[(size_t)row * CN + c];
        float2 g;
        g.x = d * acc.x + 2.f * d * zi.x + b[c];
        g.y = d * acc.y + 2.f * d * zi.y + b[c + 1];
        if (RELU) { g.x = fmaxf(g.x, 0.f); g.y = fmaxf(g.y, 0.f); }
        *(float2*)&out[(size_t)row * CN + c] = g;
    }
}

// fused: reduce AZ slices + GCN epilogue (+inv scatter)  (x4 vectorized)
__global__ void gcn_final(const float* __restrict__ Cp, int S,
                          const short* __restrict__ Zh, const short* __restrict__ Zl,
                          const float* __restrict__ rs, const float* __restrict__ b,
                          float* __restrict__ out, short* __restrict__ oh,
                          short* __restrict__ ol, int k, int C, int relu,
                          const int* __restrict__ inv, const float* __restrict__ res)
{
    int t4 = (blockIdx.x * 256 + threadIdx.x) * 4;
    int j = t4 / C, c = t4 - j * C;
    int r = inv ? inv[j] : j;
    f32x4 v = res ? *(const f32x4*)&res[t4] : (f32x4){0.f, 0.f, 0.f, 0.f};
    if (r >= 0) {
        size_t base = (size_t)r * C + c;
        size_t stride = (size_t)k * C;
        f32x4 az = {0.f, 0.f, 0.f, 0.f};
        for (int s = 0; s < S; s++) az += *(const f32x4*)&Cp[base + s * stride];
        float d = 1.f / sqrtf(rs[r] + 2.f);
        f32x4 bb = *(const f32x4*)&b[c];
#pragma unroll
        for (int q = 0; q < 4; q++) {
            size_t zi = (size_t)(c + q) * k + r;
            float zz = bf2f(Zh[zi]) + bf2f(Zl[zi]);      // zz ~= d * xw
            float g = d * az[q] + 2.f * d * zz + bb[q];
            if (relu && g < 0.f) g = 0.f;
            v[q] += g;
        }
    }
    *(f32x4*)&out[t4] = v;
    if (oh) {
        s16x4 hh, ll;
#pragma unroll
        for (int q = 0; q < 4; q++) {
            short h = f2bf(v[q]);
            hh[q] = h; ll[q] = f2bf(v[q] - bf2f(h));
        }
        *(s16x4*)&oh[t4] = hh;
        *(s16x4*)&ol[t4] = ll;
    }
}

// per-row score = tanh(x.p / ||p||); also zeroes rankb
__global__ void score_kernel(const float* __restrict__ x,
                             const float* __restrict__ p,
                             float* __restrict__ score, int n,
                             int* __restrict__ rankb)
{
    int row = blockIdx.x * 4 + (threadIdx.x >> 6);
    int lane = threadIdx.x & 63;
    float4 pv = ((const float4*)p)[lane];
    float4 xv = ((const float4*)(x + (size_t)row * 256))[lane];
    double nn  = (double)pv.x * pv.x + (double)pv.y * pv.y +
                 (double)pv.z * pv.z + (double)pv.w * pv.w;
    double acc = (double)xv.x * pv.x + (double)xv.y * pv.y +
                 (double)xv.z * pv.z + (double)xv.w * pv.w;
    for (int off = 32; off; off >>= 1) {
        acc += __shfl_down(acc, off);
        nn  += __shfl_down(nn, off);
    }
    if (lane == 0) {
        score[row] = tanhf((float)(acc / sqrt(nn)));
        rankb[row] = 0;
    }
}

__device__ __forceinline__ unsigned long long packkey(float s, int i) {
    unsigned u = __builtin_bit_cast(unsigned, s);
    u = (u & 0x80000000u) ? ~u : (u | 0x80000000u);
    return ((unsigned long long)u << 32) | (unsigned)(0xFFFFFFFFu - (unsigned)i);
}

// partial rank: block (bx,by) ranks i-chunk bx against j-chunk by
__global__ __launch_bounds__(256)
void rank_count(const float* __restrict__ score,
                int* __restrict__ rankb)
{
    __shared__ unsigned long long sk[256];
    int i = blockIdx.x * 256 + threadIdx.x;
    int j = blockIdx.y * 256 + threadIdx.x;
    sk[threadIdx.x] = packkey(score[j], j);
    unsigned long long mykey = packkey(score[i], i);
    __syncthreads();
    int part = 0;
#pragma unroll 16
    for (int q = 0; q < 256; q++) part += (sk[q] > mykey) ? 1 : 0;
    atomicAdd(&rankb[i], part);
}

// finalize: emit perm/vals (rank<k) + inv
__global__ void rank_final(const float* __restrict__ score,
                           const int* __restrict__ rankb, int k,
                           int* __restrict__ perm, float* __restrict__ vals,
                           int* __restrict__ inv)
{
    int i = blockIdx.x * 256 + threadIdx.x;
    int rank = rankb[i];
    if (rank < k) { perm[rank] = i; vals[rank] = score[i]; }
    inv[i] = (rank < k) ? rank : -1;
}

// gathered+scaled x -> hi/lo  (x4 vectorized)
__global__ void gather_x_hl(const float* __restrict__ xold,
                            const int* __restrict__ perm,
                            const float* __restrict__ vals,
                            short* __restrict__ Xh, short* __restrict__ Xl, int C)
{
    int t4 = (blockIdx.x * 256 + threadIdx.x) * 4;
    int r = t4 / C, c = t4 - r * C;
    float vv = vals[r];
    f32x4 x = *(const f32x4*)&xold[(size_t)perm[r] * C + c];
    s16x4 hh, ll;
#pragma unroll
    for (int q = 0; q < 4; q++) {
        float v = x[q] * vv;
        short h = f2bf(v);
        hh[q] = h; ll[q] = f2bf(v - bf2f(h));
    }
    *(s16x4*)&Xh[t4] = hh;
    *(s16x4*)&Xl[t4] = ll;
}

// G = (A+I)[perm,:] from bf16 A (small-int exact); zeroes rs_next  (x8 vec)
__global__ void gatherG_h(const short* __restrict__ A, int n,
                          const int* __restrict__ perm,
                          short* __restrict__ Gh, int kk,
                          float* __restrict__ rsz)
{
    int idx = blockIdx.x * 256 + threadIdx.x;
    if (idx < kk) rsz[idx] = 0.f;
    int t8 = idx * 8;
    if (t8 >= kk * n) return;
    int r = t8 / n, c0 = t8 - r * n;
    int pr = perm[r];
    bf16x8 a = *(const bf16x8*)&A[(size_t)pr * n + c0];
    if (pr >= c0 && pr < c0 + 8)
        a[pr - c0] = f2bf(bf2f(a[pr - c0]) + 1.f);
    *(bf16x8*)&Gh[t8] = a;
}

__global__ void gatherG_hl(const short* __restrict__ Ahi, const short* __restrict__ Alo,
                           int n, const int* __restrict__ perm,
                           short* __restrict__ Gh, short* __restrict__ Gl, int kk,
                           float* __restrict__ rsz)
{
    int idx = blockIdx.x * 256 + threadIdx.x;
    if (idx < kk) rsz[idx] = 0.f;
    int t8 = idx * 8;
    if (t8 >= kk * n) return;
    int r = t8 / n, c0 = t8 - r * n;
    int pr = perm[r];
    bf16x8 ah = *(const bf16x8*)&Ahi[(size_t)pr * n + c0];
    bf16x8 al = *(const bf16x8*)&Alo[(size_t)pr * n + c0];
    bf16x8 gh, gl;
#pragma unroll
    for (int q = 0; q < 8; q++) {
        float v = bf2f(ah[q]) + bf2f(al[q]) + ((c0 + q == pr) ? 1.f : 0.f);
        short h = f2bf(v);
        gh[q] = h; gl[q] = f2bf(v - bf2f(h));
    }
    *(bf16x8*)&Gh[t8] = gh;
    *(bf16x8*)&Gl[t8] = gl;
}

// fp32 mirrored slices -> A hi(/lo), rowsums  (x4 vectorized)
template<bool LO>
__global__ void aug_finish_f(const float* __restrict__ Cp, int S, int kk,
                             short* __restrict__ Ahs, short* __restrict__ Als,
                             float* __restrict__ rs)
{
    int t4 = (blockIdx.x * 256 + threadIdx.x) * 4;
    int r = t4 / kk, c0 = t4 - r * kk;
    size_t stride = (size_t)kk * kk;
    f32x4 v = {0.f, 0.f, 0.f, 0.f};
    for (int s = 0; s < S; s++) v += *(const f32x4*)&Cp[t4 + s * stride];
    if (r >= c0 && r < c0 + 4) v[r - c0] = 0.f;
    s16x4 hh, ll;
    float ws = 0.f;
#pragma unroll
    for (int q = 0; q < 4; q++) {
        short h = f2bf(v[q]);
        hh[q] = h;
        if (LO) ll[q] = f2bf(v[q] - bf2f(h));
        ws += v[q];
    }
    *(s16x4*)&Ahs[t4] = hh;
    if (LO) *(s16x4*)&Als[t4] = ll;
    for (int off = 32; off; off >>= 1) ws += __shfl_down(ws, off);
    if ((threadIdx.x & 63) == 0) atomicAdd(&rs[r], ws);
}

// ---------------------------------------------------------------------------
// Host orchestration
// ---------------------------------------------------------------------------

extern "C" void kernel_launch(void* const* d_in, const int* in_sizes, int n_in,
                              void* d_out, int out_size, void* d_ws, size_t ws_size,
                              hipStream_t stream)
{
    const float* x0  = (const float*)d_in[0];
    const int*   ei  = (const int*)d_in[1];
    const float* Wd0 = (const float*)d_in[2];  const float* bd0 = (const float*)d_in[3];
    const float* Wd1 = (const float*)d_in[4];  const float* bd1 = (const float*)d_in[5];
    const float* Wd2 = (const float*)d_in[6];  const float* bd2 = (const float*)d_in[7];
    const float* Wd3 = (const float*)d_in[8];  const float* bd3 = (const float*)d_in[9];
    const float* p1  = (const float*)d_in[10];
    const float* p2  = (const float*)d_in[11];
    const float* p3  = (const float*)d_in[12];
    const float* Wu0 = (const float*)d_in[13]; const float* bu0 = (const float*)d_in[14];
    const float* Wu1 = (const float*)d_in[15]; const float* bu1 = (const float*)d_in[16];
    const float* Wu2 = (const float*)d_in[17]; const float* bu2 = (const float*)d_in[18];

    const int E = in_sizes[1] / 2;

    char* ws = (char*)d_ws;
    size_t off = 0;
    auto alloc = [&](size_t bytes) -> void* {
        void* p = ws + off;
        off += (bytes + 255) & ~(size_t)255;
        return p;
    };
    short* A0h  = (short*)alloc((size_t)4096 * 4096 * 2);
    short* A1h  = (short*)alloc((size_t)2048 * 2048 * 2);
    short* A2h  = (short*)alloc((size_t)1024 * 1024 * 2);
    short* A2l  = (short*)alloc((size_t)1024 * 1024 * 2);
    short* A3h  = (short*)alloc((size_t)512 * 512 * 2);
    short* A3l  = (short*)alloc((size_t)512 * 512 * 2);
    short* Gh   = (short*)alloc((size_t)1024 * 2048 * 2);
    short* Gl   = (short*)alloc((size_t)512 * 1024 * 2);
    int*   csr  = (int*)alloc((size_t)4096 * 128 * 4);
    unsigned long long* maskb = (unsigned long long*)alloc((size_t)2048 * 64 * 8);
    float* Zf   = (float*)alloc((size_t)4096 * 256 * 4);
    float* Cp   = (float*)alloc((size_t)64 * 1024 * 1024);   // partial arena
    float* xs0  = (float*)alloc((size_t)4096 * 256 * 4);
    float* xs1  = (float*)alloc((size_t)2048 * 256 * 4);
    float* xs2  = (float*)alloc((size_t)1024 * 256 * 4);
    float* xu0  = (float*)alloc((size_t)4096 * 256 * 4);
    float* xu1  = (float*)alloc((size_t)2048 * 256 * 4);
    float* xu2  = (float*)alloc((size_t)1024 * 256 * 4);
    short* xu0h = (short*)alloc((size_t)4096 * 256 * 2);
    short* xu0l = (short*)alloc((size_t)4096 * 256 * 2);
    short* xu1h = (short*)alloc((size_t)2048 * 256 * 2);
    short* xu1l = (short*)alloc((size_t)2048 * 256 * 2);
    short* xu2h = (short*)alloc((size_t)1024 * 256 * 2);
    short* xu2l = (short*)alloc((size_t)1024 * 256 * 2);
    short* X0h  = (short*)alloc((size_t)4096 * 128 * 2);
    short* X0l  = (short*)alloc((size_t)4096 * 128 * 2);
    short* xah  = (short*)alloc((size_t)2048 * 256 * 2);
    short* xal  = (short*)alloc((size_t)2048 * 256 * 2);
    short* Wth  = (short*)alloc((size_t)393216 * 2);
    short* Wtl  = (short*)alloc((size_t)393216 * 2);
    short* Zh   = (short*)alloc((size_t)256 * 4096 * 2);
    short* Zl   = (short*)alloc((size_t)256 * 4096 * 2);
    float* rs0  = (float*)alloc(4096 * 4);
    float* rs1  = (float*)alloc(2048 * 4);
    float* rs2  = (float*)alloc(1024 * 4);
    float* rs3  = (float*)alloc(512 * 4);
    float* scoreb = (float*)alloc(4096 * 4);
    float* valsb  = (float*)alloc(2048 * 4);
    int*   rankb  = (int*)alloc(4096 * 4);
    int*   perm1  = (int*)alloc(2048 * 4);
    int*   perm2  = (int*)alloc(1024 * 4);
    int*   perm3  = (int*)alloc(512 * 4);
    int*   inv1   = (int*)alloc(4096 * 4);
    int*   inv2   = (int*)alloc(2048 * 4);
    int*   inv3   = (int*)alloc(1024 * 4);

    // dense-A GCN layer (levels 1..3): EPI3 xw -> z_reduce -> AZ -> gcn_final
    auto gcn_dense = [&](const short* Xh, const short* Xl, int n, int Kc, int Cout,
                         const short* pAh, const short* pAl, const float* rsA,
                         int wtoff, const float* b,
                         float* out, short* oh, short* ol, int relu, int modeA,
                         int Saz, const int* inv, const float* res, int nout) {
        int Sxw = 4;
        gemm_bt<2, 3><<<dim3(Cout / 128, n / 128, Sxw), 256, 0, stream>>>(
            Xh, Xl, Wth + wtoff, Wtl + wtoff, Cp, n, Cout, Kc, Kc / Sxw);
        z_reduce<<<(n * Cout) / 1024, 256, 0, stream>>>(Cp, Sxw, rsA, Zh, Zl, n, Cout);
        dim3 g(Cout / 128, n / 128, Saz);
        if (modeA == 1)
            gemm_bt<1, 0><<<g, 256, 0, stream>>>(pAh, nullptr, Zh, Zl, Cp, n, Cout, n, n / Saz);
        else
            gemm_bt<2, 0><<<g, 256, 0, stream>>>(pAh, pAl, Zh, Zl, Cp, n, Cout, n, n / Saz);
        gcn_final<<<(nout * Cout) / 1024, 256, 0, stream>>>(
            Cp, Saz, Zh, Zl, rsA, b, out, oh, ol, n, Cout, relu, inv, res);
    };

    auto pool = [&](const float* xlev, int n, const float* p, int* perm, int* inv) {
        int k = n / 2;
        score_kernel<<<n / 4, 256, 0, stream>>>(xlev, p, scoreb, n, rankb);
        rank_count<<<dim3(n / 256, n / 256), 256, 0, stream>>>(scoreb, rankb);
        rank_final<<<n / 256, 256, 0, stream>>>(scoreb, rankb, k, perm, valsb, inv);
        gather_x_hl<<<k / 4, 256, 0, stream>>>(xlev, perm, valsb, xah, xal, 256);
    };

    // ---- prep + adjacency + CSR ----
    prep<<<3584, 256, 0, stream>>>(Wd0, Wd1, Wd2, Wd3, Wu0, Wu1, Wu2, x0,
                                   Wth, Wtl, X0h, X0l);
    hipMemsetAsync(A0h, 0, (size_t)4096 * 4096 * 2, stream);
    build_adj_bf16<<<(E + 255) / 256, 256, 0, stream>>>(ei, E, A0h, 4096);
    row_compact<<<1024, 256, 0, stream>>>(A0h, 4096, csr, rs0);

    // ---- down 0 (A0 sparse): x@W -> Zf -> SpMM+epilogue ----
    gemm_bt<2, 0><<<dim3(2, 32, 4), 256, 0, stream>>>(
        X0h, X0l, Wth, Wtl, Cp, 4096, 256, 128, 32);
    zf_reduce<<<1024, 256, 0, stream>>>(Cp, 4, rs0, Zf, 4096, 256);
    spmm_gcn<256, 1><<<1024, 256, 0, stream>>>(csr, rs0, Zf, bd0, xs0);

    // ---- level 0 -> 1: pool + split-K bitset popcount augment ----
    pool(xs0, 4096, p1, perm1, inv1);
    build_mask<<<512, 256, 0, stream>>>(csr, rs0, perm1, maskb, rs1);
    popc_aug_p<<<dim3(32, 32, 4), 256, 0, stream>>>(maskb, (short*)Cp);
    aug_merge<<<dim3(32, 32), 256, 0, stream>>>((const short*)Cp, 2048, A1h, rs1);
    gcn_dense(xah, xal, 2048, 256, 256, A1h, nullptr, rs1, 32768, bd1,
              xs1, nullptr, nullptr, 1, 1, 16, nullptr, nullptr, 2048);

    // ---- level 1 -> 2 (dense TRI) ----
    pool(xs1, 2048, p2, perm2, inv2);
    gatherG_h<<<(1024 * 2048 / 8) / 256, 256, 0, stream>>>(A1h, 2048, perm2, Gh, 1024, rs2);
    gemm_bt<0, 1><<<dim3(8, 8, 8), 256, 0, stream>>>(Gh, nullptr, Gh, nullptr, Cp, 1024, 1024, 2048, 256);
    aug_finish_f<true><<<(1024 * 1024 / 4) / 256, 256, 0, stream>>>(Cp, 8, 1024, A2h, A2l, rs2);
    gcn_dense(xah, xal, 1024, 256, 256, A2h, A2l, rs2, 98304, bd2,
              xs2, nullptr, nullptr, 1, 2, 8, nullptr, nullptr, 1024);

    // ---- level 2 -> 3 (dense TRI) ----
    pool(xs2, 1024, p3, perm3, inv3);
    gatherG_hl<<<(512 * 1024 / 8) / 256, 256, 0, stream>>>(A2h, A2l, 1024, perm3, Gh, Gl, 512, rs3);
    gemm_bt<2, 1><<<dim3(4, 4, 8), 256, 0, stream>>>(Gh, Gl, Gh, Gl, Cp, 512, 512, 1024, 128);
    aug_finish_f<true><<<(512 * 512 / 4) / 256, 256, 0, stream>>>(Cp, 8, 512, A3h, A3l, rs3);

    // ---- down 3: out scattered into xu2 = xs2 + u (inv3) ----
    gcn_dense(xah, xal, 512, 256, 256, A3h, A3l, rs3, 163840, bd3,
              xu2, xu2h, xu2l, 1, 2, 8, inv3, xs2, 1024);

    // ---- up 0: out scattered into xu1 = xs1 + u (inv2) ----
    gcn_dense(xu2h, xu2l, 1024, 256, 256, A2h, A2l, rs2, 229376, bu0,
              xu1, xu1h, xu1l, 1, 2, 8, inv2, xs1, 2048);

    // ---- up 1: out scattered into xu0 = xs0 + u (inv1) ----
    gcn_dense(xu1h, xu1l, 2048, 256, 256, A1h, nullptr, rs1, 294912, bu1,
              xu0, xu0h, xu0l, 1, 1, 16, inv1, xs0, 4096);

    // ---- up 2 (A0 sparse, Cout=128, no relu) -> d_out ----
    gemm_bt<2, 0><<<dim3(1, 32, 8), 256, 0, stream>>>(
        xu0h, xu0l, Wth + 360448, Wtl + 360448, Cp, 4096, 128, 256, 32);
    zf_reduce<<<512, 256, 0, stream>>>(Cp, 8, rs0, Zf, 4096, 128);
    spmm_gcn<128, 0><<<1024, 256, 0, stream>>>(csr, rs0, Zf, bu2, (float*)d_out);
}

// Round 14
// 443.871 us; speedup vs baseline: 1.2319x; 1.0505x over previous
//
#include <hip/hip_runtime.h>

// ---------------------------------------------------------------------------
// GraphUNet on MI355X.  Round-14 consolidation:
//  * dense A0 replaced by 2 MB row-bitmask M0 (built by atomicOr from edges;
//    CSR+deg via wave prefix-scan compaction) — A0 dense was only feeding
//    row_compact (33.5 MB memset + scan eliminated).
//  * L0 popcount masks = gather of selected M0 rows (+self bit).
//  * Saz 16->8 for the n=2048 AZ GEMMs (halved partial-slice traffic).
// Rest identical to round 13.
// ---------------------------------------------------------------------------

typedef __attribute__((ext_vector_type(8))) short bf16x8;
typedef __attribute__((ext_vector_type(4))) short s16x4;
typedef __attribute__((ext_vector_type(4))) float f32x4;

__device__ __forceinline__ short f2bf(float f) {
    unsigned u = __builtin_bit_cast(unsigned, f);
    u += 0x7FFFu + ((u >> 16) & 1u);          // RNE
    return (short)(u >> 16);
}
__device__ __forceinline__ float bf2f(short s) {
    unsigned u = ((unsigned)(unsigned short)s) << 16;
    return __builtin_bit_cast(float, u);
}

#define GLL16(gsrc, ldst)                                                        \
    __builtin_amdgcn_global_load_lds(                                            \
        (__attribute__((address_space(1))) void*)(gsrc),                         \
        (__attribute__((address_space(3))) void*)(ldst), 16, 0, 0)

// ---------------------------------------------------------------------------
// bf16 BT GEMM: C(MxN) = A(MxK) @ B^T, B stored N x K row-major.
// MODE 0: Ah@Bh ; 1: +Ah@Bl ; 2: +Al@Bh   (lo*lo dropped, ~2^-18 rel)
// EPI 0: fp32 partial slice [z][M][N]
// EPI 1: fp32 mirrored square slices (TRI: blocks by>bx exit)
// EPI 3: fp32 TRANSPOSED partial slice [z][N][M] (f32x4 stores)
// ---------------------------------------------------------------------------
template<int MODE, int EPI>
__global__ __launch_bounds__(256, 2)
void gemm_bt(const short* __restrict__ Ah, const short* __restrict__ Al,
             const short* __restrict__ Bh, const short* __restrict__ Bl,
             float* __restrict__ Cf, int M, int N, int K, int kChunk)
{
    if (EPI == 1 && (int)blockIdx.y > (int)blockIdx.x) return;

    __shared__ short sAh[128 * 32];
    __shared__ short sBh[128 * 32];
    __shared__ short sAl[(MODE == 2) ? 128 * 32 : 8];
    __shared__ short sBl[(MODE >= 1) ? 128 * 32 : 8];

    const int t    = threadIdx.x;
    const int lane = t & 63;
    const int wave = t >> 6;
    const int tM   = blockIdx.y * 128;
    const int tN   = blockIdx.x * 128;
    const int k0   = blockIdx.z * kChunk;

    const int wm  = (wave >> 1) * 64;
    const int wn  = (wave & 1) * 64;
    const int l15 = lane & 15;
    const int g8  = (lane >> 4) * 8;

    f32x4 acc[4][4];
    const f32x4 zero = {0.f, 0.f, 0.f, 0.f};
#pragma unroll
    for (int i = 0; i < 4; i++)
#pragma unroll
        for (int j = 0; j < 4; j++) acc[i][j] = zero;

    const int i0 = t, i1 = t + 256;
    const short* a0 = Ah + (size_t)(tM + (i0 >> 2)) * K + (i0 & 3) * 8;
    const short* a1 = Ah + (size_t)(tM + (i1 >> 2)) * K + (i1 & 3) * 8;
    const short* b0 = Bh + (size_t)(tN + (i0 >> 2)) * K + (i0 & 3) * 8;
    const short* b1 = Bh + (size_t)(tN + (i1 >> 2)) * K + (i1 & 3) * 8;
    const short *bl0 = nullptr, *bl1 = nullptr, *al0 = nullptr, *al1 = nullptr;
    if (MODE >= 1) {
        bl0 = Bl + (size_t)(tN + (i0 >> 2)) * K + (i0 & 3) * 8;
        bl1 = Bl + (size_t)(tN + (i1 >> 2)) * K + (i1 & 3) * 8;
    }
    if (MODE == 2) {
        al0 = Al + (size_t)(tM + (i0 >> 2)) * K + (i0 & 3) * 8;
        al1 = Al + (size_t)(tM + (i1 >> 2)) * K + (i1 & 3) * 8;
    }

    for (int kb = k0; kb < k0 + kChunk; kb += 32) {
        GLL16(a0 + kb, &sAh[i0 * 8]);
        GLL16(a1 + kb, &sAh[i1 * 8]);
        GLL16(b0 + kb, &sBh[i0 * 8]);
        GLL16(b1 + kb, &sBh[i1 * 8]);
        if (MODE >= 1) { GLL16(bl0 + kb, &sBl[i0 * 8]); GLL16(bl1 + kb, &sBl[i1 * 8]); }
        if (MODE == 2) { GLL16(al0 + kb, &sAl[i0 * 8]); GLL16(al1 + kb, &sAl[i1 * 8]); }
        __syncthreads();

        bf16x8 aF[4], bF[4], aL[4], bL[4];
#pragma unroll
        for (int i = 0; i < 4; i++)
            aF[i] = *(const bf16x8*)&sAh[(wm + i * 16 + l15) * 32 + g8];
#pragma unroll
        for (int j = 0; j < 4; j++)
            bF[j] = *(const bf16x8*)&sBh[(wn + j * 16 + l15) * 32 + g8];
        if (MODE >= 1)
#pragma unroll
            for (int j = 0; j < 4; j++)
                bL[j] = *(const bf16x8*)&sBl[(wn + j * 16 + l15) * 32 + g8];
        if (MODE == 2)
#pragma unroll
            for (int i = 0; i < 4; i++)
                aL[i] = *(const bf16x8*)&sAl[(wm + i * 16 + l15) * 32 + g8];

#pragma unroll
        for (int i = 0; i < 4; i++)
#pragma unroll
            for (int j = 0; j < 4; j++) {
                acc[i][j] = __builtin_amdgcn_mfma_f32_16x16x32_bf16(aF[i], bF[j], acc[i][j], 0, 0, 0);
                if (MODE >= 1)
                    acc[i][j] = __builtin_amdgcn_mfma_f32_16x16x32_bf16(aF[i], bL[j], acc[i][j], 0, 0, 0);
                if (MODE == 2)
                    acc[i][j] = __builtin_amdgcn_mfma_f32_16x16x32_bf16(aL[i], bF[j], acc[i][j], 0, 0, 0);
            }
        __syncthreads();
    }

    // C/D layout: col=lane&15, row=(lane>>4)*4+reg  [m89-verified]
    const int r4 = (lane >> 4) * 4;
    if (EPI == 3) {
        float* CT = Cf + (size_t)blockIdx.z * M * N;   // [N][M]
#pragma unroll
        for (int i = 0; i < 4; i++)
#pragma unroll
            for (int j = 0; j < 4; j++) {
                const int col   = tN + wn + j * 16 + l15;
                const int rbase = tM + wm + i * 16 + r4;
                *(f32x4*)&CT[(size_t)col * M + rbase] = acc[i][j];
            }
    } else {
        float* Cg = Cf + (size_t)blockIdx.z * M * N;
#pragma unroll
        for (int i = 0; i < 4; i++)
#pragma unroll
            for (int j = 0; j < 4; j++) {
                const int col = tN + wn + j * 16 + l15;
                float* cp = Cg + (size_t)(tM + wm + i * 16 + r4) * N + col;
#pragma unroll
                for (int r = 0; r < 4; r++) cp[(size_t)r * N] = acc[i][j][r];
            }
        if (EPI == 1 && tM != tN) {
#pragma unroll
            for (int i = 0; i < 4; i++)
#pragma unroll
                for (int j = 0; j < 4; j++) {
                    const int col   = tN + wn + j * 16 + l15;
                    const int rbase = tM + wm + i * 16 + r4;
                    *(f32x4*)&Cg[(size_t)col * N + rbase] = acc[i][j];
                }
        }
    }
}

// ---------------------------------------------------------------------------
// Utility kernels
// ---------------------------------------------------------------------------

// one-shot prep: W^T hi/lo for all 7 layers + x0 hi/lo split + zero M0 bitmask
__global__ void prep(const float* __restrict__ Wd0, const float* __restrict__ Wd1,
                     const float* __restrict__ Wd2, const float* __restrict__ Wd3,
                     const float* __restrict__ Wu0, const float* __restrict__ Wu1,
                     const float* __restrict__ Wu2, const float* __restrict__ x0,
                     short* __restrict__ Wth, short* __restrict__ Wtl,
                     short* __restrict__ Xh, short* __restrict__ Xl,
                     unsigned long long* __restrict__ M0)
{
    int t = blockIdx.x * 256 + threadIdx.x;
    float v; int dst;
    if (t < 32768)       { int e = t;          v = Wd0[e]; dst = 0      + (e & 255) * 128 + (e >> 8); }
    else if (t < 98304)  { int e = t - 32768;  v = Wd1[e]; dst = 32768  + (e & 255) * 256 + (e >> 8); }
    else if (t < 163840) { int e = t - 98304;  v = Wd2[e]; dst = 98304  + (e & 255) * 256 + (e >> 8); }
    else if (t < 229376) { int e = t - 163840; v = Wd3[e]; dst = 163840 + (e & 255) * 256 + (e >> 8); }
    else if (t < 294912) { int e = t - 229376; v = Wu0[e]; dst = 229376 + (e & 255) * 256 + (e >> 8); }
    else if (t < 360448) { int e = t - 294912; v = Wu1[e]; dst = 294912 + (e & 255) * 256 + (e >> 8); }
    else if (t < 393216) { int e = t - 360448; v = Wu2[e]; dst = 360448 + (e & 127) * 256 + (e >> 7); }
    else if (t < 917504) {
        int e = t - 393216;                      // x0: 4096*128
        v = x0[e];
        short h = f2bf(v);
        Xh[e] = h; Xl[e] = f2bf(v - bf2f(h));
        return;
    } else {
        M0[t - 917504] = 0ull;                   // 4096*64 words
        return;
    }
    short h = f2bf(v);
    Wth[dst] = h; Wtl[dst] = f2bf(v - bf2f(h));
}

// edge list -> symmetric self-loop-free row bitmask (dedup for free)
__global__ void build_bits(const int* __restrict__ ei, int E,
                           unsigned long long* __restrict__ M0)
{
    int e = blockIdx.x * 256 + threadIdx.x;
    if (e >= E) return;
    int i = ei[e], j = ei[E + e];
    if (i != j) {
        atomicOr(&M0[(size_t)i * 64 + (j >> 6)], 1ull << (j & 63));
        atomicOr(&M0[(size_t)j * 64 + (i >> 6)], 1ull << (i & 63));
    }
}

// bitmask -> CSR (<=128 nnz/row, ascending) + degree, via wave prefix scan
__global__ void row_compact_bits(const unsigned long long* __restrict__ M0,
                                 int* __restrict__ csr, float* __restrict__ rs)
{
    int row = blockIdx.x * 4 + (threadIdx.x >> 6);
    int lane = threadIdx.x & 63;
    unsigned long long w = M0[(size_t)row * 64 + lane];
    int c = __popcll(w);
    int incl = c;
    for (int off = 1; off < 64; off <<= 1) {
        int v = __shfl_up(incl, off);
        if (lane >= off) incl += v;
    }
    int base = incl - c;
    int* out = csr + (size_t)row * 128;
    while (w) {
        int b = __ffsll((unsigned long long)w) - 1;
        if (base < 128) out[base] = lane * 64 + b;
        base++;
        w &= w - 1;
    }
    if (lane == 63) rs[row] = (float)incl;
}

// L0 popcount masks: gather selected M0 rows + self bit; zero rs1
__global__ void mask_gather(const unsigned long long* __restrict__ M0,
                            const int* __restrict__ perm,
                            unsigned long long* __restrict__ mask,
                            float* __restrict__ rs, int kk)
{
    int t = blockIdx.x * 256 + threadIdx.x;
    if (t < kk) rs[t] = 0.f;
    int r = t >> 6, l = t & 63;
    int u = perm[r];
    unsigned long long w = M0[(size_t)u * 64 + l];
    if ((u >> 6) == l) w |= 1ull << (u & 63);
    mask[t] = w;
}

// popcount partial: slice z covers words [z*16, z*16+16).  64x64 TRI tiles,
// 18 KB LDS -> 8 blocks/CU.  int16 partial tile at Cp[(z*1024 + by*32+bx)*4096].
#define PSTR2 18
__global__ __launch_bounds__(256, 8)
void popc_aug_p(const unsigned long long* __restrict__ mask,
                short* __restrict__ Cp)
{
    const int bx = blockIdx.x, by = blockIdx.y, z = blockIdx.z;
    if (by > bx) return;
    __shared__ unsigned long long a[64 * PSTR2];
    __shared__ unsigned long long b[64 * PSTR2];
    const int t = threadIdx.x;
#pragma unroll
    for (int p = 0; p < 4; p++) {
        int idx = p * 256 + t;           // 0..1023 = rr*16 + w
        int rr = idx >> 4, w = idx & 15;
        a[rr * PSTR2 + w] = mask[((size_t)(by * 64 + rr)) * 64 + z * 16 + w];
        b[rr * PSTR2 + w] = mask[((size_t)(bx * 64 + rr)) * 64 + z * 16 + w];
    }
    __syncthreads();
    const int i0 = (t >> 4) * 4;         // 4 consecutive rows
    const int j0 = t & 15;               // cols j0 + 16*qj
    int acc[4][4];
#pragma unroll
    for (int qi = 0; qi < 4; qi++)
#pragma unroll
        for (int qj = 0; qj < 4; qj++) acc[qi][qj] = 0;
#pragma unroll
    for (int w = 0; w < 16; w += 2) {
        ulong2 av[4], bv[4];
#pragma unroll
        for (int q = 0; q < 4; q++) av[q] = *(const ulong2*)&a[(i0 + q) * PSTR2 + w];
#pragma unroll
        for (int q = 0; q < 4; q++) bv[q] = *(const ulong2*)&b[(j0 + 16 * q) * PSTR2 + w];
#pragma unroll
        for (int qi = 0; qi < 4; qi++)
#pragma unroll
            for (int qj = 0; qj < 4; qj++) {
                acc[qi][qj] += __builtin_popcountll(av[qi].x & bv[qj].x);
                acc[qi][qj] += __builtin_popcountll(av[qi].y & bv[qj].y);
            }
    }
    short* out = Cp + ((size_t)z * 1024 + (size_t)(by * 32 + bx)) * 4096;
#pragma unroll
    for (int qi = 0; qi < 4; qi++)
#pragma unroll
        for (int qj = 0; qj < 4; qj++)
            out[(i0 + qi) * 64 + j0 + 16 * qj] = (short)acc[qi][qj];
}

// merge 4 int16 slices -> A1h (bf16, diag 0) + LDS-transposed mirror + rowsums
__global__ __launch_bounds__(256)
void aug_merge(const short* __restrict__ Cp, int kk,
               short* __restrict__ Ahs, float* __restrict__ rs)
{
    const int bx = blockIdx.x, by = blockIdx.y;
    if (by > bx) return;
    __shared__ float tile[64][65];
    __shared__ float rsum[64], csum[64];
    const int t = threadIdx.x;
    const int i  = t >> 2;               // row 0..63
    const int c0 = (t & 3) * 16;         // 16 consecutive cols
    const size_t tb = (size_t)(by * 32 + bx) * 4096;
    const size_t ss = (size_t)1024 * 4096;
    if (t < 64) { rsum[t] = 0.f; csum[t] = 0.f; }

    int v[16];
#pragma unroll
    for (int q = 0; q < 16; q++) v[q] = 0;
    for (int s = 0; s < 4; s++) {
        bf16x8 p0 = *(const bf16x8*)&Cp[tb + s * ss + i * 64 + c0];
        bf16x8 p1 = *(const bf16x8*)&Cp[tb + s * ss + i * 64 + c0 + 8];
#pragma unroll
        for (int q = 0; q < 8; q++) { v[q] += (int)p0[q]; v[8 + q] += (int)p1[q]; }
    }
    const int gi = by * 64 + i;
    float rp = 0.f;
    s16x4 pk[4];
#pragma unroll
    for (int q = 0; q < 16; q++) {
        const int gj = bx * 64 + c0 + q;
        float val = (gi == gj) ? 0.f : (float)v[q];
        tile[i][c0 + q] = val;
        rp += val;
        pk[q >> 2][q & 3] = f2bf(val);
    }
#pragma unroll
    for (int q = 0; q < 4; q++)
        *(s16x4*)&Ahs[(size_t)gi * kk + bx * 64 + c0 + q * 4] = pk[q];
    __syncthreads();
    atomicAdd(&rsum[i], rp);
    if (bx != by) {
        float cpv = 0.f;
#pragma unroll
        for (int q = 0; q < 16; q++) {
            float val = tile[c0 + q][i];
            cpv += val;
            pk[q >> 2][q & 3] = f2bf(val);
        }
#pragma unroll
        for (int q = 0; q < 4; q++)
            *(s16x4*)&Ahs[(size_t)(bx * 64 + i) * kk + by * 64 + c0 + q * 4] = pk[q];
        atomicAdd(&csum[i], cpv);
    }
    __syncthreads();
    if (t < 64) {
        atomicAdd(&rs[by * 64 + t], rsum[t]);
        if (bx != by) atomicAdd(&rs[bx * 64 + t], csum[t]);
    }
}

// reduce transposed xw partial slices -> Z^T hi/lo  (x4 vectorized)
__global__ void z_reduce(const float* __restrict__ Cp, int S,
                         const float* __restrict__ rs,
                         short* __restrict__ Zh, short* __restrict__ Zl,
                         int n, int C)
{
    int t4 = (blockIdx.x * 256 + threadIdx.x) * 4;   // t = c*n + r layout
    int r = t4 % n;
    size_t stride = (size_t)n * C;
    f32x4 v = {0.f, 0.f, 0.f, 0.f};
    for (int s = 0; s < S; s++) v += *(const f32x4*)&Cp[t4 + s * stride];
    f32x4 rsv = *(const f32x4*)&rs[r];
    s16x4 zh, zl;
#pragma unroll
    for (int q = 0; q < 4; q++) {
        float z = v[q] / sqrtf(rsv[q] + 2.f);
        short h = f2bf(z);
        zh[q] = h; zl[q] = f2bf(z - bf2f(h));
    }
    *(s16x4*)&Zh[t4] = zh;
    *(s16x4*)&Zl[t4] = zl;
}

// reduce row-major xw partial slices -> Zf fp32 [r][C]  (x4 vectorized)
__global__ void zf_reduce(const float* __restrict__ Cp, int S,
                          const float* __restrict__ rs,
                          float* __restrict__ Zf, int n, int C)
{
    int t4 = (blockIdx.x * 256 + threadIdx.x) * 4;   // t = r*C + c
    int r = t4 / C;
    size_t stride = (size_t)n * C;
    f32x4 v = {0.f, 0.f, 0.f, 0.f};
    for (int s = 0; s < S; s++) v += *(const f32x4*)&Cp[t4 + s * stride];
    float d = 1.f / sqrtf(rs[r] + 2.f);
    v *= d;
    *(f32x4*)&Zf[t4] = v;
}

// CSR SpMM + fused GCN epilogue
template<int CN, int RELU>
__global__ __launch_bounds__(256)
void spmm_gcn(const int* __restrict__ csr, const float* __restrict__ rs,
              const float* __restrict__ Zf, const float* __restrict__ b,
              float* __restrict__ out)
{
    const int lane = threadIdx.x & 63;
    const int row  = blockIdx.x * 4 + (threadIdx.x >> 6);
    const int dg   = (int)rs[row];
    const int* nb  = csr + (size_t)row * 128;
    if (CN == 256) {
        const int c = lane * 4;
        float4 acc = {0.f, 0.f, 0.f, 0.f};
        int q = 0;
        for (; q + 4 <= dg; q += 4) {
            int j0 = nb[q], j1 = nb[q+1], j2 = nb[q+2], j3 = nb[q+3];
            float4 z0 = *(const float4*)&Zf[(size_t)j0 * CN + c];
            float4 z1 = *(const float4*)&Zf[(size_t)j1 * CN + c];
            float4 z2 = *(const float4*)&Zf[(size_t)j2 * CN + c];
            float4 z3 = *(const float4*)&Zf[(size_t)j3 * CN + c];
            acc.x += z0.x; acc.y += z0.y; acc.z += z0.z; acc.w += z0.w;
            acc.x += z1.x; acc.y += z1.y; acc.z += z1.z; acc.w += z1.w;
            acc.x += z2.x; acc.y += z2.y; acc.z += z2.z; acc.w += z2.w;
            acc.x += z3.x; acc.y += z3.y; acc.z += z3.z; acc.w += z3.w;
        }
        for (; q < dg; q++) {
            float4 z = *(const float4*)&Zf[(size_t)nb[q] * CN + c];
            acc.x += z.x; acc.y += z.y; acc.z += z.z; acc.w += z.w;
        }
        float d = 1.f / sqrtf(rs[row] + 2.f);
        float4 zi = *(const float4*)&Zf[(size_t)row * CN + c];
        float4 bb = *(const float4*)&b[c];
        float4 g;
        g.x = d * acc.x + 2.f * d * zi.x + bb.x;
        g.y = d * acc.y + 2.f * d * zi.y + bb.y;
        g.z = d * acc.z + 2.f * d * zi.z + bb.z;
        g.w = d * acc.w + 2.f * d * zi.w + bb.w;
        if (RELU) {
            g.x = fmaxf(g.x, 0.f); g.y = fmaxf(g.y, 0.f);
            g.z = fmaxf(g.z, 0.f); g.w = fmaxf(g.w, 0.f);
        }
        *(float4*)&out[(size_t)row * CN + c] = g;
    } else {
        const int c = lane * 2;
        float2 acc = {0.f, 0.f};
        int q = 0;
        for (; q + 4 <= dg; q += 4) {
            int j0 = nb[q], j1 = nb[q+1], j2 = nb[q+2], j3 = nb[q+3];
            float2 z0 = *(const float2*)&Zf[(size_t)j0 * CN + c];
            float2 z1 = *(const float2*)&Zf[(size_t)j1 * CN + c];
            float2 z2 = *(const float2*)&Zf[(size_t)j2 * CN + c];
            float2 z3 = *(const float2*)&Zf[(size_t)j3 * CN + c];
            acc.x += z0.x; acc.y += z0.y;
            acc.x += z1.x; acc.y += z1.y;
            acc.x += z2.x; acc.y += z2.y;
            acc.x += z3.x; acc.y += z3.y;
        }
        for (; q < dg; q++) {
            float2 z = *(const float2*)&Zf[(size_t)nb[q] * CN + c];
            acc.x += z.x; acc.y += z.y;
        }
        float d = 1.f / sqrtf(rs[row] + 2.f);
        float2 zi = *(const float2*)&Zf[(size_t)row * CN + c];
        float2 g;
        g.x = d * acc.x + 2.f * d * zi.x + b[c];
        g.y = d * acc.y + 2.f * d * zi.y + b[c + 1];
        if (RELU) { g.x = fmaxf(g.x, 0.f); g.y = fmaxf(g.y, 0.f); }
        *(float2*)&out[(size_t)row * CN + c] = g;
    }
}

// fused: reduce AZ slices + GCN epilogue (+inv scatter)  (x4 vectorized)
__global__ void gcn_final(const float* __restrict__ Cp, int S,
                          const short* __restrict__ Zh, const short* __restrict__ Zl,
                          const float* __restrict__ rs, const float* __restrict__ b,
                          float* __restrict__ out, short* __restrict__ oh,
                          short* __restrict__ ol, int k, int C, int relu,
                          const int* __restrict__ inv, const float* __restrict__ res)
{
    int t4 = (blockIdx.x * 256 + threadIdx.x) * 4;
    int j = t4 / C, c = t4 - j * C;
    int r = inv ? inv[j] : j;
    f32x4 v = res ? *(const f32x4*)&res[t4] : (f32x4){0.f, 0.f, 0.f, 0.f};
    if (r >= 0) {
        size_t base = (size_t)r * C + c;
        size_t stride = (size_t)k * C;
        f32x4 az = {0.f, 0.f, 0.f, 0.f};
        for (int s = 0; s < S; s++) az += *(const f32x4*)&Cp[base + s * stride];
        float d = 1.f / sqrtf(rs[r] + 2.f);
        f32x4 bb = *(const f32x4*)&b[c];
#pragma unroll
        for (int q = 0; q < 4; q++) {
            size_t zi = (size_t)(c + q) * k + r;
            float zz = bf2f(Zh[zi]) + bf2f(Zl[zi]);      // zz ~= d * xw
            float g = d * az[q] + 2.f * d * zz + bb[q];
            if (relu && g < 0.f) g = 0.f;
            v[q] += g;
        }
    }
    *(f32x4*)&out[t4] = v;
    if (oh) {
        s16x4 hh, ll;
#pragma unroll
        for (int q = 0; q < 4; q++) {
            short h = f2bf(v[q]);
            hh[q] = h; ll[q] = f2bf(v[q] - bf2f(h));
        }
        *(s16x4*)&oh[t4] = hh;
        *(s16x4*)&ol[t4] = ll;
    }
}

// per-row score = tanh(x.p / ||p||); also zeroes rankb
__global__ void score_kernel(const float* __restrict__ x,
                             const float* __restrict__ p,
                             float* __restrict__ score, int n,
                             int* __restrict__ rankb)
{
    int row = blockIdx.x * 4 + (threadIdx.x >> 6);
    int lane = threadIdx.x & 63;
    float4 pv = ((const float4*)p)[lane];
    float4 xv = ((const float4*)(x + (size_t)row * 256))[lane];
    double nn  = (double)pv.x * pv.x + (double)pv.y * pv.y +
                 (double)pv.z * pv.z + (double)pv.w * pv.w;
    double acc = (double)xv.x * pv.x + (double)xv.y * pv.y +
                 (double)xv.z * pv.z + (double)xv.w * pv.w;
    for (int off = 32; off; off >>= 1) {
        acc += __shfl_down(acc, off);
        nn  += __shfl_down(nn, off);
    }
    if (lane == 0) {
        score[row] = tanhf((float)(acc / sqrt(nn)));
        rankb[row] = 0;
    }
}

__device__ __forceinline__ unsigned long long packkey(float s, int i) {
    unsigned u = __builtin_bit_cast(unsigned, s);
    u = (u & 0x80000000u) ? ~u : (u | 0x80000000u);
    return ((unsigned long long)u << 32) | (unsigned)(0xFFFFFFFFu - (unsigned)i);
}

// partial rank: block (bx,by) ranks i-chunk bx against j-chunk by
__global__ __launch_bounds__(256)
void rank_count(const float* __restrict__ score,
                int* __restrict__ rankb)
{
    __shared__ unsigned long long sk[256];
    int i = blockIdx.x * 256 + threadIdx.x;
    int j = blockIdx.y * 256 + threadIdx.x;
    sk[threadIdx.x] = packkey(score[j], j);
    unsigned long long mykey = packkey(score[i], i);
    __syncthreads();
    int part = 0;
#pragma unroll 16
    for (int q = 0; q < 256; q++) part += (sk[q] > mykey) ? 1 : 0;
    atomicAdd(&rankb[i], part);
}

// finalize: emit perm/vals (rank<k) + inv
__global__ void rank_final(const float* __restrict__ score,
                           const int* __restrict__ rankb, int k,
                           int* __restrict__ perm, float* __restrict__ vals,
                           int* __restrict__ inv)
{
    int i = blockIdx.x * 256 + threadIdx.x;
    int rank = rankb[i];
    if (rank < k) { perm[rank] = i; vals[rank] = score[i]; }
    inv[i] = (rank < k) ? rank : -1;
}

// gathered+scaled x -> hi/lo  (x4 vectorized)
__global__ void gather_x_hl(const float* __restrict__ xold,
                            const int* __restrict__ perm,
                            const float* __restrict__ vals,
                            short* __restrict__ Xh, short* __restrict__ Xl, int C)
{
    int t4 = (blockIdx.x * 256 + threadIdx.x) * 4;
    int r = t4 / C, c = t4 - r * C;
    float vv = vals[r];
    f32x4 x = *(const f32x4*)&xold[(size_t)perm[r] * C + c];
    s16x4 hh, ll;
#pragma unroll
    for (int q = 0; q < 4; q++) {
        float v = x[q] * vv;
        short h = f2bf(v);
        hh[q] = h; ll[q] = f2bf(v - bf2f(h));
    }
    *(s16x4*)&Xh[t4] = hh;
    *(s16x4*)&Xl[t4] = ll;
}

// G = (A+I)[perm,:] from bf16 A (small-int exact); zeroes rs_next  (x8 vec)
__global__ void gatherG_h(const short* __restrict__ A, int n,
                          const int* __restrict__ perm,
                          short* __restrict__ Gh, int kk,
                          float* __restrict__ rsz)
{
    int idx = blockIdx.x * 256 + threadIdx.x;
    if (idx < kk) rsz[idx] = 0.f;
    int t8 = idx * 8;
    if (t8 >= kk * n) return;
    int r = t8 / n, c0 = t8 - r * n;
    int pr = perm[r];
    bf16x8 a = *(const bf16x8*)&A[(size_t)pr * n + c0];
    if (pr >= c0 && pr < c0 + 8)
        a[pr - c0] = f2bf(bf2f(a[pr - c0]) + 1.f);
    *(bf16x8*)&Gh[t8] = a;
}

__global__ void gatherG_hl(const short* __restrict__ Ahi, const short* __restrict__ Alo,
                           int n, const int* __restrict__ perm,
                           short* __restrict__ Gh, short* __restrict__ Gl, int kk,
                           float* __restrict__ rsz)
{
    int idx = blockIdx.x * 256 + threadIdx.x;
    if (idx < kk) rsz[idx] = 0.f;
    int t8 = idx * 8;
    if (t8 >= kk * n) return;
    int r = t8 / n, c0 = t8 - r * n;
    int pr = perm[r];
    bf16x8 ah = *(const bf16x8*)&Ahi[(size_t)pr * n + c0];
    bf16x8 al = *(const bf16x8*)&Alo[(size_t)pr * n + c0];
    bf16x8 gh, gl;
#pragma unroll
    for (int q = 0; q < 8; q++) {
        float v = bf2f(ah[q]) + bf2f(al[q]) + ((c0 + q == pr) ? 1.f : 0.f);
        short h = f2bf(v);
        gh[q] = h; gl[q] = f2bf(v - bf2f(h));
    }
    *(bf16x8*)&Gh[t8] = gh;
    *(bf16x8*)&Gl[t8] = gl;
}

// fp32 mirrored slices -> A hi(/lo), rowsums  (x4 vectorized)
template<bool LO>
__global__ void aug_finish_f(const float* __restrict__ Cp, int S, int kk,
                             short* __restrict__ Ahs, short* __restrict__ Als,
                             float* __restrict__ rs)
{
    int t4 = (blockIdx.x * 256 + threadIdx.x) * 4;
    int r = t4 / kk, c0 = t4 - r * kk;
    size_t stride = (size_t)kk * kk;
    f32x4 v = {0.f, 0.f, 0.f, 0.f};
    for (int s = 0; s < S; s++) v += *(const f32x4*)&Cp[t4 + s * stride];
    if (r >= c0 && r < c0 + 4) v[r - c0] = 0.f;
    s16x4 hh, ll;
    float ws = 0.f;
#pragma unroll
    for (int q = 0; q < 4; q++) {
        short h = f2bf(v[q]);
        hh[q] = h;
        if (LO) ll[q] = f2bf(v[q] - bf2f(h));
        ws += v[q];
    }
    *(s16x4*)&Ahs[t4] = hh;
    if (LO) *(s16x4*)&Als[t4] = ll;
    for (int off = 32; off; off >>= 1) ws += __shfl_down(ws, off);
    if ((threadIdx.x & 63) == 0) atomicAdd(&rs[r], ws);
}

// ---------------------------------------------------------------------------
// Host orchestration
// ---------------------------------------------------------------------------

extern "C" void kernel_launch(void* const* d_in, const int* in_sizes, int n_in,
                              void* d_out, int out_size, void* d_ws, size_t ws_size,
                              hipStream_t stream)
{
    const float* x0  = (const float*)d_in[0];
    const int*   ei  = (const int*)d_in[1];
    const float* Wd0 = (const float*)d_in[2];  const float* bd0 = (const float*)d_in[3];
    const float* Wd1 = (const float*)d_in[4];  const float* bd1 = (const float*)d_in[5];
    const float* Wd2 = (const float*)d_in[6];  const float* bd2 = (const float*)d_in[7];
    const float* Wd3 = (const float*)d_in[8];  const float* bd3 = (const float*)d_in[9];
    const float* p1  = (const float*)d_in[10];
    const float* p2  = (const float*)d_in[11];
    const float* p3  = (const float*)d_in[12];
    const float* Wu0 = (const float*)d_in[13]; const float* bu0 = (const float*)d_in[14];
    const float* Wu1 = (const float*)d_in[15]; const float* bu1 = (const float*)d_in[16];
    const float* Wu2 = (const float*)d_in[17]; const float* bu2 = (const float*)d_in[18];

    const int E = in_sizes[1] / 2;

    char* ws = (char*)d_ws;
    size_t off = 0;
    auto alloc = [&](size_t bytes) -> void* {
        void* p = ws + off;
        off += (bytes + 255) & ~(size_t)255;
        return p;
    };
    unsigned long long* M0 = (unsigned long long*)alloc((size_t)4096 * 64 * 8);
    short* A1h  = (short*)alloc((size_t)2048 * 2048 * 2);
    short* A2h  = (short*)alloc((size_t)1024 * 1024 * 2);
    short* A2l  = (short*)alloc((size_t)1024 * 1024 * 2);
    short* A3h  = (short*)alloc((size_t)512 * 512 * 2);
    short* A3l  = (short*)alloc((size_t)512 * 512 * 2);
    short* Gh   = (short*)alloc((size_t)1024 * 2048 * 2);
    short* Gl   = (short*)alloc((size_t)512 * 1024 * 2);
    int*   csr  = (int*)alloc((size_t)4096 * 128 * 4);
    unsigned long long* maskb = (unsigned long long*)alloc((size_t)2048 * 64 * 8);
    float* Zf   = (float*)alloc((size_t)4096 * 256 * 4);
    float* Cp   = (float*)alloc((size_t)64 * 1024 * 1024);   // partial arena
    float* xs0  = (float*)alloc((size_t)4096 * 256 * 4);
    float* xs1  = (float*)alloc((size_t)2048 * 256 * 4);
    float* xs2  = (float*)alloc((size_t)1024 * 256 * 4);
    float* xu0  = (float*)alloc((size_t)4096 * 256 * 4);
    float* xu1  = (float*)alloc((size_t)2048 * 256 * 4);
    float* xu2  = (float*)alloc((size_t)1024 * 256 * 4);
    short* xu0h = (short*)alloc((size_t)4096 * 256 * 2);
    short* xu0l = (short*)alloc((size_t)4096 * 256 * 2);
    short* xu1h = (short*)alloc((size_t)2048 * 256 * 2);
    short* xu1l = (short*)alloc((size_t)2048 * 256 * 2);
    short* xu2h = (short*)alloc((size_t)1024 * 256 * 2);
    short* xu2l = (short*)alloc((size_t)1024 * 256 * 2);
    short* X0h  = (short*)alloc((size_t)4096 * 128 * 2);
    short* X0l  = (short*)alloc((size_t)4096 * 128 * 2);
    short* xah  = (short*)alloc((size_t)2048 * 256 * 2);
    short* xal  = (short*)alloc((size_t)2048 * 256 * 2);
    short* Wth  = (short*)alloc((size_t)393216 * 2);
    short* Wtl  = (short*)alloc((size_t)393216 * 2);
    short* Zh   = (short*)alloc((size_t)256 * 4096 * 2);
    short* Zl   = (short*)alloc((size_t)256 * 4096 * 2);
    float* rs0  = (float*)alloc(4096 * 4);
    float* rs1  = (float*)alloc(2048 * 4);
    float* rs2  = (float*)alloc(1024 * 4);
    float* rs3  = (float*)alloc(512 * 4);
    float* scoreb = (float*)alloc(4096 * 4);
    float* valsb  = (float*)alloc(2048 * 4);
    int*   rankb  = (int*)alloc(4096 * 4);
    int*   perm1  = (int*)alloc(2048 * 4);
    int*   perm2  = (int*)alloc(1024 * 4);
    int*   perm3  = (int*)alloc(512 * 4);
    int*   inv1   = (int*)alloc(4096 * 4);
    int*   inv2   = (int*)alloc(2048 * 4);
    int*   inv3   = (int*)alloc(1024 * 4);

    // dense-A GCN layer (levels 1..3): EPI3 xw -> z_reduce -> AZ -> gcn_final
    auto gcn_dense = [&](const short* Xh, const short* Xl, int n, int Kc, int Cout,
                         const short* pAh, const short* pAl, const float* rsA,
                         int wtoff, const float* b,
                         float* out, short* oh, short* ol, int relu, int modeA,
                         int Saz, const int* inv, const float* res, int nout) {
        int Sxw = 4;
        gemm_bt<2, 3><<<dim3(Cout / 128, n / 128, Sxw), 256, 0, stream>>>(
            Xh, Xl, Wth + wtoff, Wtl + wtoff, Cp, n, Cout, Kc, Kc / Sxw);
        z_reduce<<<(n * Cout) / 1024, 256, 0, stream>>>(Cp, Sxw, rsA, Zh, Zl, n, Cout);
        dim3 g(Cout / 128, n / 128, Saz);
        if (modeA == 1)
            gemm_bt<1, 0><<<g, 256, 0, stream>>>(pAh, nullptr, Zh, Zl, Cp, n, Cout, n, n / Saz);
        else
            gemm_bt<2, 0><<<g, 256, 0, stream>>>(pAh, pAl, Zh, Zl, Cp, n, Cout, n, n / Saz);
        gcn_final<<<(nout * Cout) / 1024, 256, 0, stream>>>(
            Cp, Saz, Zh, Zl, rsA, b, out, oh, ol, n, Cout, relu, inv, res);
    };

    auto pool = [&](const float* xlev, int n, const float* p, int* perm, int* inv) {
        int k = n / 2;
        score_kernel<<<n / 4, 256, 0, stream>>>(xlev, p, scoreb, n, rankb);
        rank_count<<<dim3(n / 256, n / 256), 256, 0, stream>>>(scoreb, rankb);
        rank_final<<<n / 256, 256, 0, stream>>>(scoreb, rankb, k, perm, valsb, inv);
        gather_x_hl<<<k / 4, 256, 0, stream>>>(xlev, perm, valsb, xah, xal, 256);
    };

    // ---- prep (weights + x0 split + M0 zero) + bitmask adjacency + CSR ----
    prep<<<4608, 256, 0, stream>>>(Wd0, Wd1, Wd2, Wd3, Wu0, Wu1, Wu2, x0,
                                   Wth, Wtl, X0h, X0l, M0);
    build_bits<<<(E + 255) / 256, 256, 0, stream>>>(ei, E, M0);
    row_compact_bits<<<1024, 256, 0, stream>>>(M0, csr, rs0);

    // ---- down 0 (A0 sparse): x@W -> Zf -> SpMM+epilogue ----
    gemm_bt<2, 0><<<dim3(2, 32, 4), 256, 0, stream>>>(
        X0h, X0l, Wth, Wtl, Cp, 4096, 256, 128, 32);
    zf_reduce<<<1024, 256, 0, stream>>>(Cp, 4, rs0, Zf, 4096, 256);
    spmm_gcn<256, 1><<<1024, 256, 0, stream>>>(csr, rs0, Zf, bd0, xs0);

    // ---- level 0 -> 1: pool + split-K bitset popcount augment ----
    pool(xs0, 4096, p1, perm1, inv1);
    mask_gather<<<512, 256, 0, stream>>>(M0, perm1, maskb, rs1, 2048);
    popc_aug_p<<<dim3(32, 32, 4), 256, 0, stream>>>(maskb, (short*)Cp);
    aug_merge<<<dim3(32, 32), 256, 0, stream>>>((const short*)Cp, 2048, A1h, rs1);
    gcn_dense(xah, xal, 2048, 256, 256, A1h, nullptr, rs1, 32768, bd1,
              xs1, nullptr, nullptr, 1, 1, 8, nullptr, nullptr, 2048);

    // ---- level 1 -> 2 (dense TRI) ----
    pool(xs1, 2048, p2, perm2, inv2);
    gatherG_h<<<(1024 * 2048 / 8) / 256, 256, 0, stream>>>(A1h, 2048, perm2, Gh, 1024, rs2);
    gemm_bt<0, 1><<<dim3(8, 8, 8), 256, 0, stream>>>(Gh, nullptr, Gh, nullptr, Cp, 1024, 1024, 2048, 256);
    aug_finish_f<true><<<(1024 * 1024 / 4) / 256, 256, 0, stream>>>(Cp, 8, 1024, A2h, A2l, rs2);
    gcn_dense(xah, xal, 1024, 256, 256, A2h, A2l, rs2, 98304, bd2,
              xs2, nullptr, nullptr, 1, 2, 8, nullptr, nullptr, 1024);

    // ---- level 2 -> 3 (dense TRI) ----
    pool(xs2, 1024, p3, perm3, inv3);
    gatherG_hl<<<(512 * 1024 / 8) / 256, 256, 0, stream>>>(A2h, A2l, 1024, perm3, Gh, Gl, 512, rs3);
    gemm_bt<2, 1><<<dim3(4, 4, 8), 256, 0, stream>>>(Gh, Gl, Gh, Gl, Cp, 512, 512, 1024, 128);
    aug_finish_f<true><<<(512 * 512 / 4) / 256, 256, 0, stream>>>(Cp, 8, 512, A3h, A3l, rs3);

    // ---- down 3: out scattered into xu2 = xs2 + u (inv3) ----
    gcn_dense(xah, xal, 512, 256, 256, A3h, A3l, rs3, 163840, bd3,
              xu2, xu2h, xu2l, 1, 2, 8, inv3, xs2, 1024);

    // ---- up 0: out scattered into xu1 = xs1 + u (inv2) ----
    gcn_dense(xu2h, xu2l, 1024, 256, 256, A2h, A2l, rs2, 229376, bu0,
              xu1, xu1h, xu1l, 1, 2, 8, inv2, xs1, 2048);

    // ---- up 1: out scattered into xu0 = xs0 + u (inv1) ----
    gcn_dense(xu1h, xu1l, 2048, 256, 256, A1h, nullptr, rs1, 294912, bu1,
              xu0, xu0h, xu0l, 1, 1, 8, inv1, xs0, 4096);

    // ---- up 2 (A0 sparse, Cout=128, no relu) -> d_out ----
    gemm_bt<2, 0><<<dim3(1, 32, 8), 256, 0, stream>>>(
        xu0h, xu0l, Wth + 360448, Wtl + 360448, Cp, 4096, 128, 256, 32);
    zf_reduce<<<512, 256, 0, stream>>>(Cp, 8, rs0, Zf, 4096, 128);
    spmm_gcn<128, 0><<<1024, 256, 0, stream>>>(csr, rs0, Zf, bu2, (float*)d_out);
}